// Round 3
// baseline (1513.514 us; speedup 1.0000x reference)
//
#include <hip/hip_runtime.h>
#include <hip/hip_bf16.h>

#define NN 50000
#define TT 16
#define DD 4
#define EE 800000
#define HH 4
#define HID 32
#define THID 64
#define HD 16

// ---------------- K1: x_pool = (mean_t x) @ in_W + in_b ----------------
__global__ __launch_bounds__(256) void pool_kernel(const float* __restrict__ x,
        const float* __restrict__ in_W, const float* __restrict__ in_b,
        float* __restrict__ xp){
    __shared__ float xs[512];
    __shared__ float xb[8][4];
    int tid = threadIdx.x;
    size_t base = (size_t)blockIdx.x * 512;
    xs[tid]       = x[base + tid];
    xs[tid + 256] = x[base + tid + 256];
    __syncthreads();
    if (tid < 32){
        int nl = tid >> 2, d = tid & 3;
        float s = 0.f;
        #pragma unroll
        for (int t = 0; t < 16; t++) s += xs[nl*64 + t*4 + d];
        xb[nl][d] = s * (1.f/16.f);
    }
    __syncthreads();
    int nl = tid >> 5, c = tid & 31;
    float v = in_b[c];
    #pragma unroll
    for (int d = 0; d < 4; d++) v += xb[nl][d] * in_W[d*32 + c];
    xp[(size_t)(blockIdx.x*8 + nl)*32 + c] = v;
}

// ---------------- CSR build ----------------
__global__ void count_kernel(const int* __restrict__ ei, int* __restrict__ counts){
    int e = blockIdx.x*256 + threadIdx.x;
    if (e >= EE) return;
    atomicAdd(&counts[ei[EE + e]], 1);
}

__global__ __launch_bounds__(1024) void scan_kernel(const int* __restrict__ counts,
                                                    int* __restrict__ offs){
    __shared__ int lds[1024];
    int tid = threadIdx.x;
    const int CH = (NN + 1023) / 1024;   // 49
    int base = tid * CH;
    int s = 0;
    for (int i = 0; i < CH; i++){
        int idx = base + i;
        if (idx < NN) s += counts[idx];
    }
    lds[tid] = s;
    __syncthreads();
    for (int off = 1; off < 1024; off <<= 1){
        int v = (tid >= off) ? lds[tid - off] : 0;
        __syncthreads();
        lds[tid] += v;
        __syncthreads();
    }
    int run = (tid == 0) ? 0 : lds[tid - 1];
    for (int i = 0; i < CH; i++){
        int idx = base + i;
        if (idx < NN){ offs[idx] = run; run += counts[idx]; }
    }
    if (tid == 1023) offs[NN] = lds[1023];
}

__global__ void copy_kernel(const int* __restrict__ a, int* __restrict__ b, int n){
    int i = blockIdx.x*256 + threadIdx.x;
    if (i < n) b[i] = a[i];
}

__global__ void fill_kernel(const int* __restrict__ ei, int* __restrict__ nxt,
                            int* __restrict__ eids){
    int e = blockIdx.x*256 + threadIdx.x;
    if (e >= EE) return;
    int dst = ei[EE + e];
    int pos = atomicAdd(&nxt[dst], 1);
    eids[pos] = e;
}

// ---------------- K2: xl = xp@Wl+bl ; xr = xp@Wr+br (8 nodes/block) ----------------
#define LNODES 8
__global__ __launch_bounds__(128) void linlr_kernel(const float* __restrict__ xp,
        const float* __restrict__ Wl, const float* __restrict__ bl,
        const float* __restrict__ Wr, const float* __restrict__ br,
        float* __restrict__ xl, float* __restrict__ xr){
    int j = threadIdx.x;
    int n0 = blockIdx.x * LNODES;
    float wl[32], wrr[32];
    #pragma unroll
    for (int k = 0; k < 32; k++){ wl[k] = Wl[k*128 + j]; wrr[k] = Wr[k*128 + j]; }
    float blv = bl[j], brv = br[j];
    __shared__ float xs[LNODES][32];
    int r = j >> 5, c = j & 31;
    #pragma unroll
    for (int q = 0; q < LNODES/4; q++)
        xs[q*4 + r][c] = xp[(size_t)(n0 + q*4 + r)*32 + c];
    __syncthreads();
    #pragma unroll
    for (int m = 0; m < LNODES; m++){
        float al = blv, ar = brv;
        #pragma unroll
        for (int k = 0; k < 32; k++){ float v = xs[m][k]; al += v*wl[k]; ar += v*wrr[k]; }
        xl[(size_t)(n0+m)*128 + j] = al;
        xr[(size_t)(n0+m)*128 + j] = ar;
    }
}

// ---------------- K3: fused GATv2 edge phase (logit+softmax+accum), CSR per dst ----------------
// softmax is shift-invariant; |logit| << 88 here so exp() without max-subtraction is safe.
__global__ __launch_bounds__(128) void gat_fused_kernel(const int* __restrict__ ei,
        const int* __restrict__ offs, const int* __restrict__ eids,
        const float* __restrict__ ew,
        const float* __restrict__ xl, const float* __restrict__ xr,
        const float* __restrict__ We, const float* __restrict__ att,
        const float* __restrict__ bias, float* __restrict__ xq){
    int n = blockIdx.x;
    int tid = threadIdx.x;        // tid = h*32 + c
    int c = tid & 31;
    float xrv  = xr[(size_t)n*128 + tid];
    float Wev  = We[tid];
    float attv = att[tid];
    int beg = offs[n], end = offs[n+1];
    float acc = 0.f, den = 0.f;
    for (int i = beg; i < end; i++){
        int e = eids[i];
        int src = ei[e];
        float w = ew[e];
        float xlv = xl[(size_t)src*128 + tid];
        float m = xlv + xrv + w*Wev;
        m = m > 0.f ? m : 0.2f*m;
        float z = m * attv;
        z += __shfl_xor(z, 1);
        z += __shfl_xor(z, 2);
        z += __shfl_xor(z, 4);
        z += __shfl_xor(z, 8);
        z += __shfl_xor(z, 16);
        float a = __expf(z);
        den += a;
        acc += a * xlv;
    }
    float v = acc / (den + 1e-16f);
    __shared__ float red[128];
    red[tid] = v;
    __syncthreads();
    if (tid < 32){
        float s = (red[c] + red[32+c] + red[64+c] + red[96+c]) * 0.25f + bias[c];
        xq[(size_t)n*32 + c] = fmaxf(s, 0.f);
    }
}

// ---------------- K9: temporal attention, wave per node, zero barriers ----------------
// Computes OUT[16] = row t of (s @ W + b) restricted to this lane's head columns.
#define PROJG(WP,BP,OUT) do{ \
    { const float4* bb = (const float4*)((BP) + h*16); \
      float4 b0 = bb[0], b1 = bb[1], b2 = bb[2], b3 = bb[3]; \
      OUT[0]=b0.x; OUT[1]=b0.y; OUT[2]=b0.z; OUT[3]=b0.w; \
      OUT[4]=b1.x; OUT[5]=b1.y; OUT[6]=b1.z; OUT[7]=b1.w; \
      OUT[8]=b2.x; OUT[9]=b2.y; OUT[10]=b2.z; OUT[11]=b2.w; \
      OUT[12]=b3.x; OUT[13]=b3.y; OUT[14]=b3.z; OUT[15]=b3.w; } \
    const float4* wrp = (const float4*)((WP) + h*16); \
    _Pragma("unroll") for (int k = 0; k < 32; k++){ \
        float sk = s[k]; \
        float4 w0 = wrp[k*16+0], w1 = wrp[k*16+1], w2 = wrp[k*16+2], w3 = wrp[k*16+3]; \
        OUT[0] += sk*w0.x; OUT[1] += sk*w0.y; OUT[2] += sk*w0.z; OUT[3] += sk*w0.w; \
        OUT[4] += sk*w1.x; OUT[5] += sk*w1.y; OUT[6] += sk*w1.z; OUT[7] += sk*w1.w; \
        OUT[8] += sk*w2.x; OUT[9] += sk*w2.y; OUT[10]+= sk*w2.z; OUT[11]+= sk*w2.w; \
        OUT[12]+= sk*w3.x; OUT[13]+= sk*w3.y; OUT[14]+= sk*w3.z; OUT[15]+= sk*w3.w; \
    } \
}while(0)

__global__ __launch_bounds__(256, 3) void temporal_kernel(const float* __restrict__ x,
        const float* __restrict__ xpool,
        const float* __restrict__ in_W, const float* __restrict__ in_b,
        const float* __restrict__ Wq, const float* __restrict__ bq,
        const float* __restrict__ Wk, const float* __restrict__ bk,
        const float* __restrict__ Wv, const float* __restrict__ bv,
        const float* __restrict__ Wo, const float* __restrict__ bo,
        float* __restrict__ out2){
    // Per-wave-private LDS quadrants; same-wave DS ops are ordered -> no __syncthreads.
    __shared__ float Klds[4][16*68];
    __shared__ float Vlds[4][16*68];
    int tid = threadIdx.x;
    int w = tid >> 6;
    int lane = tid & 63;
    int n = blockIdx.x*4 + w;
    int h = lane >> 4, t = lane & 15;

    // xpool row broadcast via shuffle (no LDS, no barrier)
    float xpv = xpool[(size_t)n*32 + (lane & 31)];

    float s[32];
    float4 xv = *(const float4*)(x + (size_t)n*64 + t*4);
    #pragma unroll
    for (int k = 0; k < 32; k++){
        s[k] = in_b[k] + __shfl(xpv, k, 64)
             + xv.x*in_W[k] + xv.y*in_W[32+k] + xv.z*in_W[64+k] + xv.w*in_W[96+k];
    }
    // K -> LDS, V -> LDS, Q stays in registers (minimizes peak live VGPRs)
    float tmp[16];
    PROJG(Wk, bk, tmp);
    #pragma unroll
    for (int d = 0; d < 16; d += 4)
        *(float4*)(&Klds[w][t*68 + h*16 + d]) = make_float4(tmp[d], tmp[d+1], tmp[d+2], tmp[d+3]);
    PROJG(Wv, bv, tmp);
    #pragma unroll
    for (int d = 0; d < 16; d += 4)
        *(float4*)(&Vlds[w][t*68 + h*16 + d]) = make_float4(tmp[d], tmp[d+1], tmp[d+2], tmp[d+3]);
    float q[16];
    PROJG(Wq, bq, q);

    float sc[16];
    #pragma unroll
    for (int t2 = 0; t2 < 16; t2++){
        const float4* kr = (const float4*)(&Klds[w][t2*68 + h*16]);
        float4 k0 = kr[0], k1 = kr[1], k2 = kr[2], k3 = kr[3];
        float dd = q[0]*k0.x + q[1]*k0.y + q[2]*k0.z + q[3]*k0.w
                 + q[4]*k1.x + q[5]*k1.y + q[6]*k1.z + q[7]*k1.w
                 + q[8]*k2.x + q[9]*k2.y + q[10]*k2.z + q[11]*k2.w
                 + q[12]*k3.x + q[13]*k3.y + q[14]*k3.z + q[15]*k3.w;
        sc[t2] = dd * 0.25f;
    }
    float mx = sc[0];
    #pragma unroll
    for (int t2 = 1; t2 < 16; t2++) mx = fmaxf(mx, sc[t2]);
    float sum = 0.f;
    #pragma unroll
    for (int t2 = 0; t2 < 16; t2++){ sc[t2] = __expf(sc[t2] - mx); sum += sc[t2]; }
    float inv = 1.f / sum;
    float cx[16];
    #pragma unroll
    for (int d = 0; d < 16; d++) cx[d] = 0.f;
    #pragma unroll
    for (int t2 = 0; t2 < 16; t2++){
        float wt = sc[t2];
        const float4* vr = (const float4*)(&Vlds[w][t2*68 + h*16]);
        float4 v0 = vr[0], v1 = vr[1], v2 = vr[2], v3 = vr[3];
        cx[0] += wt*v0.x; cx[1] += wt*v0.y; cx[2] += wt*v0.z; cx[3] += wt*v0.w;
        cx[4] += wt*v1.x; cx[5] += wt*v1.y; cx[6] += wt*v1.z; cx[7] += wt*v1.w;
        cx[8] += wt*v2.x; cx[9] += wt*v2.y; cx[10]+= wt*v2.z; cx[11]+= wt*v2.w;
        cx[12]+= wt*v3.x; cx[13]+= wt*v3.y; cx[14]+= wt*v3.z; cx[15]+= wt*v3.w;
    }
    #pragma unroll
    for (int d = 0; d < 16; d++) cx[d] *= inv;
    // stage ctx into this wave's Klds quadrant (same-wave ordering: reads above done first)
    {
        float4* cw = (float4*)(&Klds[w][t*68 + h*16]);
        cw[0] = make_float4(cx[0], cx[1], cx[2], cx[3]);
        cw[1] = make_float4(cx[4], cx[5], cx[6], cx[7]);
        cw[2] = make_float4(cx[8], cx[9], cx[10], cx[11]);
        cw[3] = make_float4(cx[12], cx[13], cx[14], cx[15]);
    }
    int t_o = lane & 15, g = lane >> 4;
    float acc[8];
    {
        const float4* bo4 = (const float4*)(bo + g*8);
        float4 b0 = bo4[0], b1 = bo4[1];
        acc[0]=b0.x; acc[1]=b0.y; acc[2]=b0.z; acc[3]=b0.w;
        acc[4]=b1.x; acc[5]=b1.y; acc[6]=b1.z; acc[7]=b1.w;
    }
    #pragma unroll
    for (int j4 = 0; j4 < 16; j4++){
        float4 c4 = *(const float4*)(&Klds[w][t_o*68 + j4*4]);
        #pragma unroll
        for (int jj = 0; jj < 4; jj++){
            float cj = (jj==0)?c4.x:(jj==1)?c4.y:(jj==2)?c4.z:c4.w;
            const float4* wo4 = (const float4*)(Wo + (size_t)(j4*4+jj)*32 + g*8);
            float4 wa = wo4[0], wb = wo4[1];
            acc[0] += cj*wa.x; acc[1] += cj*wa.y; acc[2] += cj*wa.z; acc[3] += cj*wa.w;
            acc[4] += cj*wb.x; acc[5] += cj*wb.y; acc[6] += cj*wb.z; acc[7] += cj*wb.w;
        }
    }
    float* outp = out2 + ((size_t)t_o*NN + n)*32 + g*8;
    *(float4*)outp       = make_float4(acc[0], acc[1], acc[2], acc[3]);
    *((float4*)outp + 1) = make_float4(acc[4], acc[5], acc[6], acc[7]);
}

// ---------------- K10: forecast / risk heads ----------------
__global__ __launch_bounds__(256) void head_kernel(const float* __restrict__ out2,
        const float* __restrict__ fW1, const float* __restrict__ fb1,
        const float* __restrict__ fW2, const float* __restrict__ fb2,
        const float* __restrict__ rW1, const float* __restrict__ rb1,
        const float* __restrict__ rW2, const float* __restrict__ rb2,
        float* __restrict__ out0, float* __restrict__ out1){
    int tid = threadIdx.x;
    int wv = tid >> 6, lane = tid & 63;
    int n = blockIdx.x*4 + wv;
    int c = lane & 31, path = lane >> 5;
    const float* W1 = path ? rW1 : fW1;
    const float* b1 = path ? rb1 : fb1;
    const float* W2 = path ? rW2 : fW2;
    const float* b2 = path ? rb2 : fb2;
    const float* last = out2 + ((size_t)15*NN + n)*32;
    float h1 = b1[c];
    #pragma unroll
    for (int k = 0; k < 32; k++) h1 += last[k] * W1[k*32 + c];
    h1 = fmaxf(h1, 0.f);
    float z = h1 * W2[c];
    #pragma unroll
    for (int off = 16; off >= 1; off >>= 1) z += __shfl_xor(z, off, 64);
    if (lane == 0)  out0[n] = fmaxf(z + b2[0], 0.f);
    if (lane == 32) out1[n] = 1.f / (1.f + __expf(-(z + b2[0])));
}

extern "C" void kernel_launch(void* const* d_in, const int* in_sizes, int n_in,
                              void* d_out, int out_size, void* d_ws, size_t ws_size,
                              hipStream_t stream){
    const float* x    = (const float*)d_in[0];
    const int*   ei   = (const int*)  d_in[1];
    const float* ew   = (const float*)d_in[2];
    const float* in_W = (const float*)d_in[3];
    const float* in_b = (const float*)d_in[4];
    const float* Wq = (const float*)d_in[19];
    const float* bq = (const float*)d_in[20];
    const float* Wk = (const float*)d_in[21];
    const float* bk = (const float*)d_in[22];
    const float* Wv = (const float*)d_in[23];
    const float* bv = (const float*)d_in[24];
    const float* Wo = (const float*)d_in[25];
    const float* bo = (const float*)d_in[26];
    const float* fW1 = (const float*)d_in[27];
    const float* fb1 = (const float*)d_in[28];
    const float* fW2 = (const float*)d_in[29];
    const float* fb2 = (const float*)d_in[30];
    const float* rW1 = (const float*)d_in[31];
    const float* rb1 = (const float*)d_in[32];
    const float* rW2 = (const float*)d_in[33];
    const float* rb2 = (const float*)d_in[34];

    float* out0 = (float*)d_out;
    float* out1 = out0 + NN;
    float* out2 = out0 + 2*NN;

    float* ws = (float*)d_ws;
    size_t off = 0;
    float* xl     = ws + off; off += (size_t)NN*128;
    float* xr     = ws + off; off += (size_t)NN*128;
    float* xpA    = ws + off; off += (size_t)NN*32;
    float* xpB    = ws + off; off += (size_t)NN*32;
    int* counts   = (int*)(ws + off); off += NN;
    int* offs     = (int*)(ws + off); off += NN + 1;
    int* nxt      = (int*)(ws + off); off += NN + 1;
    int* eids     = (int*)(ws + off); off += EE;

    hipMemsetAsync(counts, 0, NN*sizeof(int), stream);
    pool_kernel<<<NN/8, 256, 0, stream>>>(x, in_W, in_b, xpA);
    count_kernel<<<(EE+255)/256, 256, 0, stream>>>(ei, counts);
    scan_kernel<<<1, 1024, 0, stream>>>(counts, offs);
    copy_kernel<<<(NN+255)/256, 256, 0, stream>>>(offs, nxt, NN);
    fill_kernel<<<(EE+255)/256, 256, 0, stream>>>(ei, nxt, eids);

    for (int layer = 0; layer < 2; layer++){
        const float* Wl   = (const float*)d_in[5 + 7*layer];
        const float* bl   = (const float*)d_in[6 + 7*layer];
        const float* Wr   = (const float*)d_in[7 + 7*layer];
        const float* br   = (const float*)d_in[8 + 7*layer];
        const float* We   = (const float*)d_in[9 + 7*layer];
        const float* att  = (const float*)d_in[10 + 7*layer];
        const float* bias = (const float*)d_in[11 + 7*layer];
        const float* xin  = layer ? xpB : xpA;
        float*       xout = layer ? xpA : xpB;
        linlr_kernel<<<NN/LNODES, 128, 0, stream>>>(xin, Wl, bl, Wr, br, xl, xr);
        gat_fused_kernel<<<NN, 128, 0, stream>>>(ei, offs, eids, ew, xl, xr, We, att, bias, xout);
    }

    temporal_kernel<<<NN/4, 256, 0, stream>>>(x, xpA, in_W, in_b,
                                              Wq, bq, Wk, bk, Wv, bv, Wo, bo, out2);
    head_kernel<<<NN/4, 256, 0, stream>>>(out2, fW1, fb1, fW2, fb2,
                                          rW1, rb1, rW2, rb2, out0, out1);
}

// Round 4
// 1369.134 us; speedup vs baseline: 1.1055x; 1.1055x over previous
//
#include <hip/hip_runtime.h>
#include <hip/hip_bf16.h>

#define NN 50000
#define TT 16
#define DD 4
#define EE 800000
#define HH 4
#define HID 32
#define THID 64
#define HD 16

// ---------------- K1: x_pool = (mean_t x) @ in_W + in_b ----------------
__global__ __launch_bounds__(256) void pool_kernel(const float* __restrict__ x,
        const float* __restrict__ in_W, const float* __restrict__ in_b,
        float* __restrict__ xp){
    __shared__ float xs[512];
    __shared__ float xb[8][4];
    int tid = threadIdx.x;
    size_t base = (size_t)blockIdx.x * 512;
    xs[tid]       = x[base + tid];
    xs[tid + 256] = x[base + tid + 256];
    __syncthreads();
    if (tid < 32){
        int nl = tid >> 2, d = tid & 3;
        float s = 0.f;
        #pragma unroll
        for (int t = 0; t < 16; t++) s += xs[nl*64 + t*4 + d];
        xb[nl][d] = s * (1.f/16.f);
    }
    __syncthreads();
    int nl = tid >> 5, c = tid & 31;
    float v = in_b[c];
    #pragma unroll
    for (int d = 0; d < 4; d++) v += xb[nl][d] * in_W[d*32 + c];
    xp[(size_t)(blockIdx.x*8 + nl)*32 + c] = v;
}

// ---------------- CSR build ----------------
__global__ void count_kernel(const int* __restrict__ ei, int* __restrict__ counts){
    int e = blockIdx.x*256 + threadIdx.x;
    if (e >= EE) return;
    atomicAdd(&counts[ei[EE + e]], 1);
}

// writes both offs and nxt (removes the separate copy kernel)
__global__ __launch_bounds__(1024) void scan_kernel(const int* __restrict__ counts,
                                                    int* __restrict__ offs,
                                                    int* __restrict__ nxt){
    __shared__ int lds[1024];
    int tid = threadIdx.x;
    const int CH = (NN + 1023) / 1024;   // 49
    int base = tid * CH;
    int s = 0;
    for (int i = 0; i < CH; i++){
        int idx = base + i;
        if (idx < NN) s += counts[idx];
    }
    lds[tid] = s;
    __syncthreads();
    for (int off = 1; off < 1024; off <<= 1){
        int v = (tid >= off) ? lds[tid - off] : 0;
        __syncthreads();
        lds[tid] += v;
        __syncthreads();
    }
    int run = (tid == 0) ? 0 : lds[tid - 1];
    for (int i = 0; i < CH; i++){
        int idx = base + i;
        if (idx < NN){ offs[idx] = run; nxt[idx] = run; run += counts[idx]; }
    }
    if (tid == 1023) offs[NN] = lds[1023];
}

__global__ void fill_kernel(const int* __restrict__ ei, int* __restrict__ nxt,
                            int* __restrict__ eids){
    int e = blockIdx.x*256 + threadIdx.x;
    if (e >= EE) return;
    int dst = ei[EE + e];
    int pos = atomicAdd(&nxt[dst], 1);
    eids[pos] = e;
}

// ---------------- K2: xl = xp@Wl+bl ; xr = xp@Wr+br (8 nodes/block) ----------------
#define LNODES 8
__global__ __launch_bounds__(128) void linlr_kernel(const float* __restrict__ xp,
        const float* __restrict__ Wl, const float* __restrict__ bl,
        const float* __restrict__ Wr, const float* __restrict__ br,
        float* __restrict__ xl, float* __restrict__ xr){
    int j = threadIdx.x;
    int n0 = blockIdx.x * LNODES;
    float wl[32], wrr[32];
    #pragma unroll
    for (int k = 0; k < 32; k++){ wl[k] = Wl[k*128 + j]; wrr[k] = Wr[k*128 + j]; }
    float blv = bl[j], brv = br[j];
    __shared__ float xs[LNODES][32];
    int r = j >> 5, c = j & 31;
    #pragma unroll
    for (int q = 0; q < LNODES/4; q++)
        xs[q*4 + r][c] = xp[(size_t)(n0 + q*4 + r)*32 + c];
    __syncthreads();
    #pragma unroll
    for (int m = 0; m < LNODES; m++){
        float al = blv, ar = brv;
        #pragma unroll
        for (int k = 0; k < 32; k++){ float v = xs[m][k]; al += v*wl[k]; ar += v*wrr[k]; }
        xl[(size_t)(n0+m)*128 + j] = al;
        xr[(size_t)(n0+m)*128 + j] = ar;
    }
}

// ---------------- K3: fused GATv2 edge phase (logit+softmax+accum), CSR per dst ----------------
// softmax is shift-invariant; |logit| << 88 here so exp() without max-subtraction is safe.
__global__ __launch_bounds__(128) void gat_fused_kernel(const int* __restrict__ ei,
        const int* __restrict__ offs, const int* __restrict__ eids,
        const float* __restrict__ ew,
        const float* __restrict__ xl, const float* __restrict__ xr,
        const float* __restrict__ We, const float* __restrict__ att,
        const float* __restrict__ bias, float* __restrict__ xq){
    int n = blockIdx.x;
    int tid = threadIdx.x;        // tid = h*32 + c
    int c = tid & 31;
    float xrv  = xr[(size_t)n*128 + tid];
    float Wev  = We[tid];
    float attv = att[tid];
    int beg = offs[n], end = offs[n+1];
    float acc = 0.f, den = 0.f;
    for (int i = beg; i < end; i++){
        int e = eids[i];
        int src = ei[e];
        float w = ew[e];
        float xlv = xl[(size_t)src*128 + tid];
        float m = xlv + xrv + w*Wev;
        m = m > 0.f ? m : 0.2f*m;
        float z = m * attv;
        z += __shfl_xor(z, 1);
        z += __shfl_xor(z, 2);
        z += __shfl_xor(z, 4);
        z += __shfl_xor(z, 8);
        z += __shfl_xor(z, 16);
        float a = __expf(z);
        den += a;
        acc += a * xlv;
    }
    float v = acc / (den + 1e-16f);
    __shared__ float red[128];
    red[tid] = v;
    __syncthreads();
    if (tid < 32){
        float s = (red[c] + red[32+c] + red[64+c] + red[96+c]) * 0.25f + bias[c];
        xq[(size_t)n*32 + c] = fmaxf(s, 0.f);
    }
}

// ---------------- K9: temporal attention, wave per node, zero barriers ----------------
// NOTE: do NOT pass a min-waves arg to __launch_bounds__ here — hipcc caps
// VGPR at 256/w (architected 256 file, not gfx950's 512) and spills:
// (256,4)->64 VGPR/387MB scratch, (256,3)->84 VGPR/607MB scratch. Uncapped
// allocation is ~136 VGPR, zero scratch.
#define PROJG(WP,BP,OUT) do{ \
    { const float4* bb = (const float4*)((BP) + h*16); \
      float4 b0 = bb[0], b1 = bb[1], b2 = bb[2], b3 = bb[3]; \
      OUT[0]=b0.x; OUT[1]=b0.y; OUT[2]=b0.z; OUT[3]=b0.w; \
      OUT[4]=b1.x; OUT[5]=b1.y; OUT[6]=b1.z; OUT[7]=b1.w; \
      OUT[8]=b2.x; OUT[9]=b2.y; OUT[10]=b2.z; OUT[11]=b2.w; \
      OUT[12]=b3.x; OUT[13]=b3.y; OUT[14]=b3.z; OUT[15]=b3.w; } \
    const float4* wrp = (const float4*)((WP) + h*16); \
    _Pragma("unroll") for (int k = 0; k < 32; k++){ \
        float sk = s[k]; \
        float4 w0 = wrp[k*16+0], w1 = wrp[k*16+1], w2 = wrp[k*16+2], w3 = wrp[k*16+3]; \
        OUT[0] += sk*w0.x; OUT[1] += sk*w0.y; OUT[2] += sk*w0.z; OUT[3] += sk*w0.w; \
        OUT[4] += sk*w1.x; OUT[5] += sk*w1.y; OUT[6] += sk*w1.z; OUT[7] += sk*w1.w; \
        OUT[8] += sk*w2.x; OUT[9] += sk*w2.y; OUT[10]+= sk*w2.z; OUT[11]+= sk*w2.w; \
        OUT[12]+= sk*w3.x; OUT[13]+= sk*w3.y; OUT[14]+= sk*w3.z; OUT[15]+= sk*w3.w; \
    } \
}while(0)

__global__ __launch_bounds__(256) void temporal_kernel(const float* __restrict__ x,
        const float* __restrict__ xpool,
        const float* __restrict__ in_W, const float* __restrict__ in_b,
        const float* __restrict__ Wq, const float* __restrict__ bq,
        const float* __restrict__ Wk, const float* __restrict__ bk,
        const float* __restrict__ Wv, const float* __restrict__ bv,
        const float* __restrict__ Wo, const float* __restrict__ bo,
        float* __restrict__ out2){
    // Per-wave-private LDS quadrants; same-wave DS ops are ordered -> no __syncthreads.
    __shared__ float Klds[4][16*68];
    __shared__ float Vlds[4][16*68];
    int tid = threadIdx.x;
    int w = tid >> 6;
    int lane = tid & 63;
    int n = blockIdx.x*4 + w;
    int h = lane >> 4, t = lane & 15;

    // xpool row broadcast via shuffle (no LDS, no barrier)
    float xpv = xpool[(size_t)n*32 + (lane & 31)];

    float s[32];
    float4 xv = *(const float4*)(x + (size_t)n*64 + t*4);
    #pragma unroll
    for (int k = 0; k < 32; k++){
        s[k] = in_b[k] + __shfl(xpv, k, 64)
             + xv.x*in_W[k] + xv.y*in_W[32+k] + xv.z*in_W[64+k] + xv.w*in_W[96+k];
    }
    // K -> LDS, V -> LDS, Q stays in registers (minimizes peak live VGPRs)
    float tmp[16];
    PROJG(Wk, bk, tmp);
    #pragma unroll
    for (int d = 0; d < 16; d += 4)
        *(float4*)(&Klds[w][t*68 + h*16 + d]) = make_float4(tmp[d], tmp[d+1], tmp[d+2], tmp[d+3]);
    PROJG(Wv, bv, tmp);
    #pragma unroll
    for (int d = 0; d < 16; d += 4)
        *(float4*)(&Vlds[w][t*68 + h*16 + d]) = make_float4(tmp[d], tmp[d+1], tmp[d+2], tmp[d+3]);
    float q[16];
    PROJG(Wq, bq, q);

    float sc[16];
    #pragma unroll
    for (int t2 = 0; t2 < 16; t2++){
        const float4* kr = (const float4*)(&Klds[w][t2*68 + h*16]);
        float4 k0 = kr[0], k1 = kr[1], k2 = kr[2], k3 = kr[3];
        float dd = q[0]*k0.x + q[1]*k0.y + q[2]*k0.z + q[3]*k0.w
                 + q[4]*k1.x + q[5]*k1.y + q[6]*k1.z + q[7]*k1.w
                 + q[8]*k2.x + q[9]*k2.y + q[10]*k2.z + q[11]*k2.w
                 + q[12]*k3.x + q[13]*k3.y + q[14]*k3.z + q[15]*k3.w;
        sc[t2] = dd * 0.25f;
    }
    float mx = sc[0];
    #pragma unroll
    for (int t2 = 1; t2 < 16; t2++) mx = fmaxf(mx, sc[t2]);
    float sum = 0.f;
    #pragma unroll
    for (int t2 = 0; t2 < 16; t2++){ sc[t2] = __expf(sc[t2] - mx); sum += sc[t2]; }
    float inv = 1.f / sum;
    float cx[16];
    #pragma unroll
    for (int d = 0; d < 16; d++) cx[d] = 0.f;
    #pragma unroll
    for (int t2 = 0; t2 < 16; t2++){
        float wt = sc[t2];
        const float4* vr = (const float4*)(&Vlds[w][t2*68 + h*16]);
        float4 v0 = vr[0], v1 = vr[1], v2 = vr[2], v3 = vr[3];
        cx[0] += wt*v0.x; cx[1] += wt*v0.y; cx[2] += wt*v0.z; cx[3] += wt*v0.w;
        cx[4] += wt*v1.x; cx[5] += wt*v1.y; cx[6] += wt*v1.z; cx[7] += wt*v1.w;
        cx[8] += wt*v2.x; cx[9] += wt*v2.y; cx[10]+= wt*v2.z; cx[11]+= wt*v2.w;
        cx[12]+= wt*v3.x; cx[13]+= wt*v3.y; cx[14]+= wt*v3.z; cx[15]+= wt*v3.w;
    }
    #pragma unroll
    for (int d = 0; d < 16; d++) cx[d] *= inv;
    // stage ctx into this wave's Klds quadrant (same-wave ordering: reads above done first)
    {
        float4* cw = (float4*)(&Klds[w][t*68 + h*16]);
        cw[0] = make_float4(cx[0], cx[1], cx[2], cx[3]);
        cw[1] = make_float4(cx[4], cx[5], cx[6], cx[7]);
        cw[2] = make_float4(cx[8], cx[9], cx[10], cx[11]);
        cw[3] = make_float4(cx[12], cx[13], cx[14], cx[15]);
    }
    int t_o = lane & 15, g = lane >> 4;
    float acc[8];
    {
        const float4* bo4 = (const float4*)(bo + g*8);
        float4 b0 = bo4[0], b1 = bo4[1];
        acc[0]=b0.x; acc[1]=b0.y; acc[2]=b0.z; acc[3]=b0.w;
        acc[4]=b1.x; acc[5]=b1.y; acc[6]=b1.z; acc[7]=b1.w;
    }
    #pragma unroll
    for (int j4 = 0; j4 < 16; j4++){
        float4 c4 = *(const float4*)(&Klds[w][t_o*68 + j4*4]);
        #pragma unroll
        for (int jj = 0; jj < 4; jj++){
            float cj = (jj==0)?c4.x:(jj==1)?c4.y:(jj==2)?c4.z:c4.w;
            const float4* wo4 = (const float4*)(Wo + (size_t)(j4*4+jj)*32 + g*8);
            float4 wa = wo4[0], wb = wo4[1];
            acc[0] += cj*wa.x; acc[1] += cj*wa.y; acc[2] += cj*wa.z; acc[3] += cj*wa.w;
            acc[4] += cj*wb.x; acc[5] += cj*wb.y; acc[6] += cj*wb.z; acc[7] += cj*wb.w;
        }
    }
    float* outp = out2 + ((size_t)t_o*NN + n)*32 + g*8;
    *(float4*)outp       = make_float4(acc[0], acc[1], acc[2], acc[3]);
    *((float4*)outp + 1) = make_float4(acc[4], acc[5], acc[6], acc[7]);
}

// ---------------- K10: forecast / risk heads ----------------
__global__ __launch_bounds__(256) void head_kernel(const float* __restrict__ out2,
        const float* __restrict__ fW1, const float* __restrict__ fb1,
        const float* __restrict__ fW2, const float* __restrict__ fb2,
        const float* __restrict__ rW1, const float* __restrict__ rb1,
        const float* __restrict__ rW2, const float* __restrict__ rb2,
        float* __restrict__ out0, float* __restrict__ out1){
    int tid = threadIdx.x;
    int wv = tid >> 6, lane = tid & 63;
    int n = blockIdx.x*4 + wv;
    int c = lane & 31, path = lane >> 5;
    const float* W1 = path ? rW1 : fW1;
    const float* b1 = path ? rb1 : fb1;
    const float* W2 = path ? rW2 : fW2;
    const float* b2 = path ? rb2 : fb2;
    const float* last = out2 + ((size_t)15*NN + n)*32;
    float h1 = b1[c];
    #pragma unroll
    for (int k = 0; k < 32; k++) h1 += last[k] * W1[k*32 + c];
    h1 = fmaxf(h1, 0.f);
    float z = h1 * W2[c];
    #pragma unroll
    for (int off = 16; off >= 1; off >>= 1) z += __shfl_xor(z, off, 64);
    if (lane == 0)  out0[n] = fmaxf(z + b2[0], 0.f);
    if (lane == 32) out1[n] = 1.f / (1.f + __expf(-(z + b2[0])));
}

extern "C" void kernel_launch(void* const* d_in, const int* in_sizes, int n_in,
                              void* d_out, int out_size, void* d_ws, size_t ws_size,
                              hipStream_t stream){
    const float* x    = (const float*)d_in[0];
    const int*   ei   = (const int*)  d_in[1];
    const float* ew   = (const float*)d_in[2];
    const float* in_W = (const float*)d_in[3];
    const float* in_b = (const float*)d_in[4];
    const float* Wq = (const float*)d_in[19];
    const float* bq = (const float*)d_in[20];
    const float* Wk = (const float*)d_in[21];
    const float* bk = (const float*)d_in[22];
    const float* Wv = (const float*)d_in[23];
    const float* bv = (const float*)d_in[24];
    const float* Wo = (const float*)d_in[25];
    const float* bo = (const float*)d_in[26];
    const float* fW1 = (const float*)d_in[27];
    const float* fb1 = (const float*)d_in[28];
    const float* fW2 = (const float*)d_in[29];
    const float* fb2 = (const float*)d_in[30];
    const float* rW1 = (const float*)d_in[31];
    const float* rb1 = (const float*)d_in[32];
    const float* rW2 = (const float*)d_in[33];
    const float* rb2 = (const float*)d_in[34];

    float* out0 = (float*)d_out;
    float* out1 = out0 + NN;
    float* out2 = out0 + 2*NN;

    float* ws = (float*)d_ws;
    size_t off = 0;
    float* xl     = ws + off; off += (size_t)NN*128;
    float* xr     = ws + off; off += (size_t)NN*128;
    float* xpA    = ws + off; off += (size_t)NN*32;
    float* xpB    = ws + off; off += (size_t)NN*32;
    int* counts   = (int*)(ws + off); off += NN;
    int* offs     = (int*)(ws + off); off += NN + 1;
    int* nxt      = (int*)(ws + off); off += NN + 1;
    int* eids     = (int*)(ws + off); off += EE;

    hipMemsetAsync(counts, 0, NN*sizeof(int), stream);
    pool_kernel<<<NN/8, 256, 0, stream>>>(x, in_W, in_b, xpA);
    count_kernel<<<(EE+255)/256, 256, 0, stream>>>(ei, counts);
    scan_kernel<<<1, 1024, 0, stream>>>(counts, offs, nxt);
    fill_kernel<<<(EE+255)/256, 256, 0, stream>>>(ei, nxt, eids);

    for (int layer = 0; layer < 2; layer++){
        const float* Wl   = (const float*)d_in[5 + 7*layer];
        const float* bl   = (const float*)d_in[6 + 7*layer];
        const float* Wr   = (const float*)d_in[7 + 7*layer];
        const float* br   = (const float*)d_in[8 + 7*layer];
        const float* We   = (const float*)d_in[9 + 7*layer];
        const float* att  = (const float*)d_in[10 + 7*layer];
        const float* bias = (const float*)d_in[11 + 7*layer];
        const float* xin  = layer ? xpB : xpA;
        float*       xout = layer ? xpA : xpB;
        linlr_kernel<<<NN/LNODES, 128, 0, stream>>>(xin, Wl, bl, Wr, br, xl, xr);
        gat_fused_kernel<<<NN, 128, 0, stream>>>(ei, offs, eids, ew, xl, xr, We, att, bias, xout);
    }

    temporal_kernel<<<NN/4, 256, 0, stream>>>(x, xpA, in_W, in_b,
                                              Wq, bq, Wk, bk, Wv, bv, Wo, bo, out2);
    head_kernel<<<NN/4, 256, 0, stream>>>(out2, fW1, fb1, fW2, fb2,
                                          rW1, rb1, rW2, rb2, out0, out1);
}

// Round 5
// 726.516 us; speedup vs baseline: 2.0832x; 1.8845x over previous
//
#include <hip/hip_runtime.h>
#include <hip/hip_bf16.h>

#define NN 50000
#define TT 16
#define DD 4
#define EE 800000
#define HH 4
#define HID 32
#define THID 64
#define HD 16

typedef __attribute__((ext_vector_type(8))) short bf16x8;
typedef __attribute__((ext_vector_type(4))) float f32x4;
typedef __attribute__((ext_vector_type(4))) unsigned u32x4;

__device__ __forceinline__ unsigned short f2bf(float f){
    unsigned u = __float_as_uint(f);
    u = u + 0x7fffu + ((u >> 16) & 1u);   // RNE
    return (unsigned short)(u >> 16);
}
__device__ __forceinline__ unsigned pk2(float a, float b){
    return (unsigned)f2bf(a) | ((unsigned)f2bf(b) << 16);
}
__device__ __forceinline__ bf16x8 mk8(unsigned a0, unsigned a1, unsigned a2, unsigned a3){
    u32x4 u = {a0, a1, a2, a3};
    return __builtin_bit_cast(bf16x8, u);
}
// Build an 8-bf16 operand fragment from a C-fragment's packed dword pair via 4 shfls.
__device__ __forceinline__ bf16x8 gather8(int d0, int d1, int s0, int s1, bool zero){
    int a0 = __shfl(d0, s0, 64);
    int a1 = __shfl(d1, s0, 64);
    int a2 = __shfl(d0, s1, 64);
    int a3 = __shfl(d1, s1, 64);
    if (zero){ a0 = 0; a1 = 0; a2 = 0; a3 = 0; }
    return mk8((unsigned)a0, (unsigned)a1, (unsigned)a2, (unsigned)a3);
}

// ---------------- K1: x_pool = (mean_t x) @ in_W + in_b ----------------
__global__ __launch_bounds__(256) void pool_kernel(const float* __restrict__ x,
        const float* __restrict__ in_W, const float* __restrict__ in_b,
        float* __restrict__ xp){
    __shared__ float xs[512];
    __shared__ float xb[8][4];
    int tid = threadIdx.x;
    size_t base = (size_t)blockIdx.x * 512;
    xs[tid]       = x[base + tid];
    xs[tid + 256] = x[base + tid + 256];
    __syncthreads();
    if (tid < 32){
        int nl = tid >> 2, d = tid & 3;
        float s = 0.f;
        #pragma unroll
        for (int t = 0; t < 16; t++) s += xs[nl*64 + t*4 + d];
        xb[nl][d] = s * (1.f/16.f);
    }
    __syncthreads();
    int nl = tid >> 5, c = tid & 31;
    float v = in_b[c];
    #pragma unroll
    for (int d = 0; d < 4; d++) v += xb[nl][d] * in_W[d*32 + c];
    xp[(size_t)(blockIdx.x*8 + nl)*32 + c] = v;
}

// ---------------- weight -> bf16 MFMA fragments (once per launch) ----------------
// frag[fid][lane][j]: fid 0-3 Wq^T blk, 4-7 Wk^T blk, 8-11 Wv blk, 12-15 Wo^T (rb*2+ks)
// value = W[k0 + (lane>>4)*8 + j][16*b + (lane&15)]  (same formula serves A- and B-frags)
__global__ void wfrag_kernel(const float* __restrict__ Wq, const float* __restrict__ Wk,
                             const float* __restrict__ Wv, const float* __restrict__ Wo,
                             unsigned short* __restrict__ frag){
    int fid = blockIdx.x, lane = threadIdx.x;
    const float* W; int b, k0, ncol;
    if (fid < 4)      { W = Wq; b = fid;      k0 = 0;  ncol = 64; }
    else if (fid < 8) { W = Wk; b = fid - 4;  k0 = 0;  ncol = 64; }
    else if (fid < 12){ W = Wv; b = fid - 8;  k0 = 0;  ncol = 64; }
    else { W = Wo; int rb = (fid-12) >> 1, ks = (fid-12) & 1; b = rb; k0 = ks*32; ncol = 32; }
    int col = 16*b + (lane & 15);
    int kk  = k0 + (lane >> 4)*8;
    unsigned short* out = frag + ((size_t)fid*64 + lane)*8;
    #pragma unroll
    for (int j = 0; j < 8; j++) out[j] = f2bf(W[(size_t)(kk + j)*ncol + col]);
}

// ---------------- CSR build ----------------
__global__ void count_kernel(const int* __restrict__ ei, int* __restrict__ counts){
    int e = blockIdx.x*256 + threadIdx.x;
    if (e >= EE) return;
    atomicAdd(&counts[ei[EE + e]], 1);
}

__global__ __launch_bounds__(1024) void scan_kernel(const int* __restrict__ counts,
                                                    int* __restrict__ offs,
                                                    int* __restrict__ nxt){
    __shared__ int lds[1024];
    int tid = threadIdx.x;
    const int CH = (NN + 1023) / 1024;   // 49
    int base = tid * CH;
    int s = 0;
    for (int i = 0; i < CH; i++){
        int idx = base + i;
        if (idx < NN) s += counts[idx];
    }
    lds[tid] = s;
    __syncthreads();
    for (int off = 1; off < 1024; off <<= 1){
        int v = (tid >= off) ? lds[tid - off] : 0;
        __syncthreads();
        lds[tid] += v;
        __syncthreads();
    }
    int run = (tid == 0) ? 0 : lds[tid - 1];
    for (int i = 0; i < CH; i++){
        int idx = base + i;
        if (idx < NN){ offs[idx] = run; nxt[idx] = run; run += counts[idx]; }
    }
    if (tid == 1023) offs[NN] = lds[1023];
}

__global__ void fill_kernel(const int* __restrict__ ei, int* __restrict__ nxt,
                            int* __restrict__ eids){
    int e = blockIdx.x*256 + threadIdx.x;
    if (e >= EE) return;
    int dst = ei[EE + e];
    int pos = atomicAdd(&nxt[dst], 1);
    eids[pos] = e;
}

// ---------------- K2: xl = xp@Wl+bl ; xr = xp@Wr+br (8 nodes/block) ----------------
#define LNODES 8
__global__ __launch_bounds__(128) void linlr_kernel(const float* __restrict__ xp,
        const float* __restrict__ Wl, const float* __restrict__ bl,
        const float* __restrict__ Wr, const float* __restrict__ br,
        float* __restrict__ xl, float* __restrict__ xr){
    int j = threadIdx.x;
    int n0 = blockIdx.x * LNODES;
    float wl[32], wrr[32];
    #pragma unroll
    for (int k = 0; k < 32; k++){ wl[k] = Wl[k*128 + j]; wrr[k] = Wr[k*128 + j]; }
    float blv = bl[j], brv = br[j];
    __shared__ float xs[LNODES][32];
    int r = j >> 5, c = j & 31;
    #pragma unroll
    for (int q = 0; q < LNODES/4; q++)
        xs[q*4 + r][c] = xp[(size_t)(n0 + q*4 + r)*32 + c];
    __syncthreads();
    #pragma unroll
    for (int m = 0; m < LNODES; m++){
        float al = blv, ar = brv;
        #pragma unroll
        for (int k = 0; k < 32; k++){ float v = xs[m][k]; al += v*wl[k]; ar += v*wrr[k]; }
        xl[(size_t)(n0+m)*128 + j] = al;
        xr[(size_t)(n0+m)*128 + j] = ar;
    }
}

// ---------------- K3: fused GATv2 edge phase ----------------
__global__ __launch_bounds__(128) void gat_fused_kernel(const int* __restrict__ ei,
        const int* __restrict__ offs, const int* __restrict__ eids,
        const float* __restrict__ ew,
        const float* __restrict__ xl, const float* __restrict__ xr,
        const float* __restrict__ We, const float* __restrict__ att,
        const float* __restrict__ bias, float* __restrict__ xq){
    int n = blockIdx.x;
    int tid = threadIdx.x;        // tid = h*32 + c
    int c = tid & 31;
    float xrv  = xr[(size_t)n*128 + tid];
    float Wev  = We[tid];
    float attv = att[tid];
    int beg = offs[n], end = offs[n+1];
    float acc = 0.f, den = 0.f;
    for (int i = beg; i < end; i++){
        int e = eids[i];
        int src = ei[e];
        float w = ew[e];
        float xlv = xl[(size_t)src*128 + tid];
        float m = xlv + xrv + w*Wev;
        m = m > 0.f ? m : 0.2f*m;
        float z = m * attv;
        z += __shfl_xor(z, 1);
        z += __shfl_xor(z, 2);
        z += __shfl_xor(z, 4);
        z += __shfl_xor(z, 8);
        z += __shfl_xor(z, 16);
        float a = __expf(z);
        den += a;
        acc += a * xlv;
    }
    float v = acc / (den + 1e-16f);
    __shared__ float red[128];
    red[tid] = v;
    __syncthreads();
    if (tid < 32){
        float s = (red[c] + red[32+c] + red[64+c] + red[96+c]) * 0.25f + bias[c];
        xq[(size_t)n*32 + c] = fmaxf(s, 0.f);
    }
}

// ---------------- K9: temporal attention via MFMA, one wave per node ----------------
// Chain: s-frag -> (Q^T,K^T,V proj MFMA) -> scores^T MFMA -> softmax -> PV MFMA
//        -> LDS transpose -> Wo MFMA -> LDS transpose -> coalesced store.
// A/B k-order within a lane-group cancels between A and B (any consistent bijection
// is correct); only the C layout (col=lane&15, row=4*(lane>>4)+reg) is relied upon.
__global__ __launch_bounds__(256) void temporal_kernel(const float* __restrict__ x,
        const float* __restrict__ xpool,
        const float* __restrict__ in_W, const float* __restrict__ in_b,
        const float* __restrict__ bq, const float* __restrict__ bk,
        const float* __restrict__ bv, const float* __restrict__ bo,
        const unsigned short* __restrict__ wfrag,
        float* __restrict__ out2){
    __shared__ float ctxL[4][64][18];   // padded: all access patterns <=2-way (free)
    int tid = threadIdx.x, w = tid >> 6, lane = tid & 63;
    int n = blockIdx.x*4 + w;
    int t = lane & 15, g = lane >> 4;
    int k0 = g * 8;

    // ---- x_seq fragment (row t, k-slice k0..k0+7), serves as A- or B-operand ----
    f32x4 xv  = *(const f32x4*)(x + (size_t)n*64 + t*4);
    f32x4 ib0 = *(const f32x4*)(in_b + k0);
    f32x4 ib1 = *(const f32x4*)(in_b + k0 + 4);
    f32x4 xp0 = *(const f32x4*)(xpool + (size_t)n*32 + k0);
    f32x4 xp1 = *(const f32x4*)(xpool + (size_t)n*32 + k0 + 4);
    f32x4 iw0a = *(const f32x4*)(in_W + k0),      iw0b = *(const f32x4*)(in_W + k0 + 4);
    f32x4 iw1a = *(const f32x4*)(in_W + 32 + k0), iw1b = *(const f32x4*)(in_W + 32 + k0 + 4);
    f32x4 iw2a = *(const f32x4*)(in_W + 64 + k0), iw2b = *(const f32x4*)(in_W + 64 + k0 + 4);
    f32x4 iw3a = *(const f32x4*)(in_W + 96 + k0), iw3b = *(const f32x4*)(in_W + 96 + k0 + 4);
    f32x4 sA = ib0 + xp0 + xv[0]*iw0a + xv[1]*iw1a + xv[2]*iw2a + xv[3]*iw3a;
    f32x4 sB = ib1 + xp1 + xv[0]*iw0b + xv[1]*iw1b + xv[2]*iw2b + xv[3]*iw3b;
    bf16x8 sfrag = mk8(pk2(sA[0],sA[1]), pk2(sA[2],sA[3]), pk2(sB[0],sB[1]), pk2(sB[2],sB[3]));

    const bf16x8* WF = (const bf16x8*)wfrag;
    f32x4 zero = {0.f, 0.f, 0.f, 0.f};

    // ---- projections: Q^T, K^T (transposed), V (normal) ----
    int qd0[4], qd1[4], kd0[4], kd1[4], vd0[4], vd1[4];
    #pragma unroll
    for (int b = 0; b < 4; b++){
        bf16x8 wq = WF[(0*4 + b)*64 + lane];
        bf16x8 wk = WF[(1*4 + b)*64 + lane];
        bf16x8 wv = WF[(2*4 + b)*64 + lane];
        f32x4 qc = __builtin_amdgcn_mfma_f32_16x16x32_bf16(wq, sfrag, zero, 0, 0, 0);
        f32x4 kc = __builtin_amdgcn_mfma_f32_16x16x32_bf16(wk, sfrag, zero, 0, 0, 0);
        f32x4 vc = __builtin_amdgcn_mfma_f32_16x16x32_bf16(sfrag, wv, zero, 0, 0, 0);
        f32x4 bq4 = *(const f32x4*)(bq + 16*b + 4*g);   // Q^T rows = d_local
        f32x4 bk4 = *(const f32x4*)(bk + 16*b + 4*g);
        float bvv = bv[16*b + t];                        // V cols = d_local (= lane&15)
        qc += bq4; kc += bk4;
        vc[0] += bvv; vc[1] += bvv; vc[2] += bvv; vc[3] += bvv;
        qd0[b] = (int)pk2(qc[0], qc[1]); qd1[b] = (int)pk2(qc[2], qc[3]);
        kd0[b] = (int)pk2(kc[0], kc[1]); kd1[b] = (int)pk2(kc[2], kc[3]);
        vd0[b] = (int)pk2(vc[0], vc[1]); vd1[b] = (int)pk2(vc[2], vc[3]);
    }

    // ---- per-head: scores^T = K @ Q^T (K-dim 16, zero-padded to 32), softmax, PV ----
    int s0l = t + 32*(g & 1);
    int s1l = s0l + 16;
    bool hiz = (g >= 2);
    #pragma unroll
    for (int h = 0; h < 4; h++){
        bf16x8 ka = gather8(kd0[h], kd1[h], s0l, s1l, hiz);
        bf16x8 qb = gather8(qd0[h], qd1[h], s0l, s1l, hiz);
        f32x4 sc = __builtin_amdgcn_mfma_f32_16x16x32_bf16(ka, qb, zero, 0, 0, 0);
        sc *= 0.25f;   // scale = HD^-0.5
        float m = fmaxf(fmaxf(sc[0], sc[1]), fmaxf(sc[2], sc[3]));
        m = fmaxf(m, __shfl_xor(m, 16, 64));
        m = fmaxf(m, __shfl_xor(m, 32, 64));
        float p0 = __expf(sc[0] - m), p1 = __expf(sc[1] - m);
        float p2 = __expf(sc[2] - m), p3 = __expf(sc[3] - m);
        float sum = p0 + p1 + p2 + p3;
        sum += __shfl_xor(sum, 16, 64);
        sum += __shfl_xor(sum, 32, 64);
        float inv = 1.f / sum;
        int pd0 = (int)pk2(p0, p1), pd1 = (int)pk2(p2, p3);
        bf16x8 va = gather8(vd0[h], vd1[h], s0l, s1l, hiz);
        bf16x8 pb = gather8(pd0, pd1, s0l, s1l, hiz);
        f32x4 cx = __builtin_amdgcn_mfma_f32_16x16x32_bf16(va, pb, zero, 0, 0, 0);
        cx *= inv;
        #pragma unroll
        for (int r = 0; r < 4; r++) ctxL[w][h*16 + 4*g + r][t] = cx[r];
    }

    // ---- ctx^T -> B-frag (K=32) via LDS, then out^T = Wo^T @ ctx^T ----
    bf16x8 cb[2];
    #pragma unroll
    for (int ks = 0; ks < 2; ks++){
        float c0 = ctxL[w][ks*32 + k0 + 0][t], c1 = ctxL[w][ks*32 + k0 + 1][t];
        float c2 = ctxL[w][ks*32 + k0 + 2][t], c3 = ctxL[w][ks*32 + k0 + 3][t];
        float c4 = ctxL[w][ks*32 + k0 + 4][t], c5 = ctxL[w][ks*32 + k0 + 5][t];
        float c6 = ctxL[w][ks*32 + k0 + 6][t], c7 = ctxL[w][ks*32 + k0 + 7][t];
        cb[ks] = mk8(pk2(c0,c1), pk2(c2,c3), pk2(c4,c5), pk2(c6,c7));
    }
    #pragma unroll
    for (int rb = 0; rb < 2; rb++){
        bf16x8 wo0 = WF[(12 + rb*2 + 0)*64 + lane];
        bf16x8 wo1 = WF[(12 + rb*2 + 1)*64 + lane];
        f32x4 oc = __builtin_amdgcn_mfma_f32_16x16x32_bf16(wo0, cb[0], zero, 0, 0, 0);
        oc = __builtin_amdgcn_mfma_f32_16x16x32_bf16(wo1, cb[1], oc, 0, 0, 0);
        f32x4 bo4 = *(const f32x4*)(bo + 16*rb + 4*g);
        oc += bo4;
        #pragma unroll
        for (int r = 0; r < 4; r++) ctxL[w][16*rb + 4*g + r][t] = oc[r];
    }
    // ---- transpose out^T -> per-lane contiguous c, coalesced float4 stores ----
    float o[8];
    #pragma unroll
    for (int j = 0; j < 8; j++) o[j] = ctxL[w][g*8 + j][t];
    float* outp = out2 + ((size_t)t*NN + n)*32 + g*8;
    *(f32x4*)outp       = (f32x4){o[0], o[1], o[2], o[3]};
    *((f32x4*)outp + 1) = (f32x4){o[4], o[5], o[6], o[7]};
}

// ---------------- K10: forecast / risk heads ----------------
__global__ __launch_bounds__(256) void head_kernel(const float* __restrict__ out2,
        const float* __restrict__ fW1, const float* __restrict__ fb1,
        const float* __restrict__ fW2, const float* __restrict__ fb2,
        const float* __restrict__ rW1, const float* __restrict__ rb1,
        const float* __restrict__ rW2, const float* __restrict__ rb2,
        float* __restrict__ out0, float* __restrict__ out1){
    int tid = threadIdx.x;
    int wv = tid >> 6, lane = tid & 63;
    int n = blockIdx.x*4 + wv;
    int c = lane & 31, path = lane >> 5;
    const float* W1 = path ? rW1 : fW1;
    const float* b1 = path ? rb1 : fb1;
    const float* W2 = path ? rW2 : fW2;
    const float* b2 = path ? rb2 : fb2;
    const float* last = out2 + ((size_t)15*NN + n)*32;
    float h1 = b1[c];
    #pragma unroll
    for (int k = 0; k < 32; k++) h1 += last[k] * W1[k*32 + c];
    h1 = fmaxf(h1, 0.f);
    float z = h1 * W2[c];
    #pragma unroll
    for (int off = 16; off >= 1; off >>= 1) z += __shfl_xor(z, off, 64);
    if (lane == 0)  out0[n] = fmaxf(z + b2[0], 0.f);
    if (lane == 32) out1[n] = 1.f / (1.f + __expf(-(z + b2[0])));
}

extern "C" void kernel_launch(void* const* d_in, const int* in_sizes, int n_in,
                              void* d_out, int out_size, void* d_ws, size_t ws_size,
                              hipStream_t stream){
    const float* x    = (const float*)d_in[0];
    const int*   ei   = (const int*)  d_in[1];
    const float* ew   = (const float*)d_in[2];
    const float* in_W = (const float*)d_in[3];
    const float* in_b = (const float*)d_in[4];
    const float* Wq = (const float*)d_in[19];
    const float* bq = (const float*)d_in[20];
    const float* Wk = (const float*)d_in[21];
    const float* bk = (const float*)d_in[22];
    const float* Wv = (const float*)d_in[23];
    const float* bv = (const float*)d_in[24];
    const float* Wo = (const float*)d_in[25];
    const float* bo = (const float*)d_in[26];
    const float* fW1 = (const float*)d_in[27];
    const float* fb1 = (const float*)d_in[28];
    const float* fW2 = (const float*)d_in[29];
    const float* fb2 = (const float*)d_in[30];
    const float* rW1 = (const float*)d_in[31];
    const float* rb1 = (const float*)d_in[32];
    const float* rW2 = (const float*)d_in[33];
    const float* rb2 = (const float*)d_in[34];

    float* out0 = (float*)d_out;
    float* out1 = out0 + NN;
    float* out2 = out0 + 2*NN;

    float* ws = (float*)d_ws;
    size_t off = 0;
    float* xl     = ws + off; off += (size_t)NN*128;
    float* xr     = ws + off; off += (size_t)NN*128;
    float* xpA    = ws + off; off += (size_t)NN*32;
    float* xpB    = ws + off; off += (size_t)NN*32;
    int* counts   = (int*)(ws + off); off += NN;
    int* offs     = (int*)(ws + off); off += NN + 1;
    int* nxt      = (int*)(ws + off); off += NN + 1;
    int* eids     = (int*)(ws + off); off += EE;
    off = (off + 3) & ~(size_t)3;            // 16B align for bf16x8 loads
    unsigned short* wfrag = (unsigned short*)(ws + off); off += 16*64*8/2;

    hipMemsetAsync(counts, 0, NN*sizeof(int), stream);
    pool_kernel<<<NN/8, 256, 0, stream>>>(x, in_W, in_b, xpA);
    wfrag_kernel<<<16, 64, 0, stream>>>(Wq, Wk, Wv, Wo, wfrag);
    count_kernel<<<(EE+255)/256, 256, 0, stream>>>(ei, counts);
    scan_kernel<<<1, 1024, 0, stream>>>(counts, offs, nxt);
    fill_kernel<<<(EE+255)/256, 256, 0, stream>>>(ei, nxt, eids);

    for (int layer = 0; layer < 2; layer++){
        const float* Wl   = (const float*)d_in[5 + 7*layer];
        const float* bl   = (const float*)d_in[6 + 7*layer];
        const float* Wr   = (const float*)d_in[7 + 7*layer];
        const float* br   = (const float*)d_in[8 + 7*layer];
        const float* We   = (const float*)d_in[9 + 7*layer];
        const float* att  = (const float*)d_in[10 + 7*layer];
        const float* bias = (const float*)d_in[11 + 7*layer];
        const float* xin  = layer ? xpB : xpA;
        float*       xout = layer ? xpA : xpB;
        linlr_kernel<<<NN/LNODES, 128, 0, stream>>>(xin, Wl, bl, Wr, br, xl, xr);
        gat_fused_kernel<<<NN, 128, 0, stream>>>(ei, offs, eids, ew, xl, xr, We, att, bias, xout);
    }

    temporal_kernel<<<NN/4, 256, 0, stream>>>(x, xpA, in_W, in_b,
                                              bq, bk, bv, bo, wfrag, out2);
    head_kernel<<<NN/4, 256, 0, stream>>>(out2, fW1, fb1, fW2, fb2,
                                          rW1, rb1, rW2, rb2, out0, out1);
}

// Round 6
// 577.933 us; speedup vs baseline: 2.6188x; 1.2571x over previous
//
#include <hip/hip_runtime.h>
#include <hip/hip_bf16.h>

#define NN 50000
#define TT 16
#define DD 4
#define EE 800000
#define HH 4
#define HID 32
#define THID 64
#define HD 16

typedef __attribute__((ext_vector_type(8))) short bf16x8;
typedef __attribute__((ext_vector_type(4))) float f32x4;
typedef __attribute__((ext_vector_type(4))) unsigned u32x4;

__device__ __forceinline__ unsigned short f2bf(float f){
    unsigned u = __float_as_uint(f);
    u = u + 0x7fffu + ((u >> 16) & 1u);   // RNE
    return (unsigned short)(u >> 16);
}
__device__ __forceinline__ unsigned pk2(float a, float b){
    return (unsigned)f2bf(a) | ((unsigned)f2bf(b) << 16);
}
__device__ __forceinline__ bf16x8 mk8(unsigned a0, unsigned a1, unsigned a2, unsigned a3){
    u32x4 u = {a0, a1, a2, a3};
    return __builtin_bit_cast(bf16x8, u);
}
// Build an 8-bf16 operand fragment from a C-fragment's packed dword pair via 4 shfls.
__device__ __forceinline__ bf16x8 gather8(int d0, int d1, int s0, int s1, bool zero){
    int a0 = __shfl(d0, s0, 64);
    int a1 = __shfl(d1, s0, 64);
    int a2 = __shfl(d0, s1, 64);
    int a3 = __shfl(d1, s1, 64);
    if (zero){ a0 = 0; a1 = 0; a2 = 0; a3 = 0; }
    return mk8((unsigned)a0, (unsigned)a1, (unsigned)a2, (unsigned)a3);
}

// ---------------- K1: x_pool = (mean_t x) @ in_W + in_b ----------------
__global__ __launch_bounds__(256) void pool_kernel(const float* __restrict__ x,
        const float* __restrict__ in_W, const float* __restrict__ in_b,
        float* __restrict__ xp){
    __shared__ float xs[512];
    __shared__ float xb[8][4];
    int tid = threadIdx.x;
    size_t base = (size_t)blockIdx.x * 512;
    xs[tid]       = x[base + tid];
    xs[tid + 256] = x[base + tid + 256];
    __syncthreads();
    if (tid < 32){
        int nl = tid >> 2, d = tid & 3;
        float s = 0.f;
        #pragma unroll
        for (int t = 0; t < 16; t++) s += xs[nl*64 + t*4 + d];
        xb[nl][d] = s * (1.f/16.f);
    }
    __syncthreads();
    int nl = tid >> 5, c = tid & 31;
    float v = in_b[c];
    #pragma unroll
    for (int d = 0; d < 4; d++) v += xb[nl][d] * in_W[d*32 + c];
    xp[(size_t)(blockIdx.x*8 + nl)*32 + c] = v;
}

// ---------------- weight -> bf16 MFMA fragments (once per launch) ----------------
__global__ void wfrag_kernel(const float* __restrict__ Wq, const float* __restrict__ Wk,
                             const float* __restrict__ Wv, const float* __restrict__ Wo,
                             unsigned short* __restrict__ frag){
    int fid = blockIdx.x, lane = threadIdx.x;
    const float* W; int b, k0, ncol;
    if (fid < 4)      { W = Wq; b = fid;      k0 = 0;  ncol = 64; }
    else if (fid < 8) { W = Wk; b = fid - 4;  k0 = 0;  ncol = 64; }
    else if (fid < 12){ W = Wv; b = fid - 8;  k0 = 0;  ncol = 64; }
    else { W = Wo; int rb = (fid-12) >> 1, ks = (fid-12) & 1; b = rb; k0 = ks*32; ncol = 32; }
    int col = 16*b + (lane & 15);
    int kk  = k0 + (lane >> 4)*8;
    unsigned short* out = frag + ((size_t)fid*64 + lane)*8;
    #pragma unroll
    for (int j = 0; j < 8; j++) out[j] = f2bf(W[(size_t)(kk + j)*ncol + col]);
}

// ---------------- CSR build ----------------
__global__ void count_kernel(const int* __restrict__ ei, int* __restrict__ counts){
    int e = blockIdx.x*256 + threadIdx.x;
    if (e >= EE) return;
    atomicAdd(&counts[ei[EE + e]], 1);
}

__global__ __launch_bounds__(1024) void scan_kernel(const int* __restrict__ counts,
                                                    int* __restrict__ offs,
                                                    int* __restrict__ nxt){
    __shared__ int lds[1024];
    int tid = threadIdx.x;
    const int CH = (NN + 1023) / 1024;   // 49
    int base = tid * CH;
    int s = 0;
    for (int i = 0; i < CH; i++){
        int idx = base + i;
        if (idx < NN) s += counts[idx];
    }
    lds[tid] = s;
    __syncthreads();
    for (int off = 1; off < 1024; off <<= 1){
        int v = (tid >= off) ? lds[tid - off] : 0;
        __syncthreads();
        lds[tid] += v;
        __syncthreads();
    }
    int run = (tid == 0) ? 0 : lds[tid - 1];
    for (int i = 0; i < CH; i++){
        int idx = base + i;
        if (idx < NN){ offs[idx] = run; nxt[idx] = run; run += counts[idx]; }
    }
    if (tid == 1023) offs[NN] = lds[1023];
}

// materialize CSR-ordered (src, weight) records -> 2-deep load chain in gat kernel
__global__ void fill_kernel(const int* __restrict__ ei, const float* __restrict__ ew,
                            int* __restrict__ nxt, int2* __restrict__ esrc){
    int e = blockIdx.x*256 + threadIdx.x;
    if (e >= EE) return;
    int dst = ei[EE + e];
    int pos = atomicAdd(&nxt[dst], 1);
    esrc[pos] = make_int2(ei[e], __float_as_int(ew[e]));
}

// ---------------- K2: xl(bf16) = xp@Wl+bl ; xr(f32) = xp@Wr+br ----------------
#define LNODES 8
__global__ __launch_bounds__(128) void linlr_kernel(const float* __restrict__ xp,
        const float* __restrict__ Wl, const float* __restrict__ bl,
        const float* __restrict__ Wr, const float* __restrict__ br,
        unsigned short* __restrict__ xlb, float* __restrict__ xr){
    int j = threadIdx.x;
    int n0 = blockIdx.x * LNODES;
    float wl[32], wrr[32];
    #pragma unroll
    for (int k = 0; k < 32; k++){ wl[k] = Wl[k*128 + j]; wrr[k] = Wr[k*128 + j]; }
    float blv = bl[j], brv = br[j];
    __shared__ float xs[LNODES][32];
    int r = j >> 5, c = j & 31;
    #pragma unroll
    for (int q = 0; q < LNODES/4; q++)
        xs[q*4 + r][c] = xp[(size_t)(n0 + q*4 + r)*32 + c];
    __syncthreads();
    #pragma unroll
    for (int m = 0; m < LNODES; m++){
        float al = blv, ar = brv;
        #pragma unroll
        for (int k = 0; k < 32; k++){ float v = xs[m][k]; al += v*wl[k]; ar += v*wrr[k]; }
        xlb[(size_t)(n0+m)*128 + j] = f2bf(al);
        xr[(size_t)(n0+m)*128 + j] = ar;
    }
}

// ---------------- K3: fused GATv2 edge phase, 4 waves strided over edges ----------------
// lane holds channels (2*lane, 2*lane+1); head = lane>>4; 16-lane shfl reduce -> logit.
// softmax shift-invariance: |logit| small, exp() without max-subtraction is safe.
__global__ __launch_bounds__(256) void gat_fused_kernel(
        const int* __restrict__ offs, const int2* __restrict__ esrc,
        const unsigned short* __restrict__ xlb, const float* __restrict__ xr,
        const float* __restrict__ We, const float* __restrict__ att,
        const float* __restrict__ bias, float* __restrict__ xq){
    int n = blockIdx.x;
    int tid = threadIdx.x;
    int w = tid >> 6, lane = tid & 63;
    int c2 = lane << 1;
    float2 xrv  = *(const float2*)(xr + (size_t)n*128 + c2);
    float2 Wev  = *(const float2*)(We + c2);
    float2 attv = *(const float2*)(att + c2);
    int beg = offs[n], end = offs[n+1];
    float acc0 = 0.f, acc1 = 0.f, den = 0.f;
    for (int i = beg + w; i < end; i += 4){
        int2 r = esrc[i];
        int src  = r.x;
        float wt = __int_as_float(r.y);
        unsigned u = *(const unsigned*)(xlb + (size_t)src*128 + c2);
        float xl0 = __uint_as_float(u << 16);
        float xl1 = __uint_as_float(u & 0xffff0000u);
        float m0 = xl0 + xrv.x + wt*Wev.x; m0 = m0 > 0.f ? m0 : 0.2f*m0;
        float m1 = xl1 + xrv.y + wt*Wev.y; m1 = m1 > 0.f ? m1 : 0.2f*m1;
        float z = m0*attv.x + m1*attv.y;
        z += __shfl_xor(z, 1);
        z += __shfl_xor(z, 2);
        z += __shfl_xor(z, 4);
        z += __shfl_xor(z, 8);
        float a = __expf(z);
        den += a; acc0 += a*xl0; acc1 += a*xl1;
    }
    __shared__ float lacc[4][64][2];
    __shared__ float lden[4][64];
    lacc[w][lane][0] = acc0;
    lacc[w][lane][1] = acc1;
    lden[w][lane] = den;
    __syncthreads();
    if (tid < 32){
        float s = 0.f;
        #pragma unroll
        for (int h = 0; h < 4; h++){
            int l = 16*h + (tid >> 1), sl = tid & 1;
            float a = lacc[0][l][sl] + lacc[1][l][sl] + lacc[2][l][sl] + lacc[3][l][sl];
            float d = lden[0][l] + lden[1][l] + lden[2][l] + lden[3][l];
            s += a / (d + 1e-16f);
        }
        s = s*0.25f + bias[tid];
        xq[(size_t)n*32 + tid] = fmaxf(s, 0.f);
    }
}

// ---------------- K9: temporal attention via MFMA, one wave per node ----------------
__global__ __launch_bounds__(256) void temporal_kernel(const float* __restrict__ x,
        const float* __restrict__ xpool,
        const float* __restrict__ in_W, const float* __restrict__ in_b,
        const float* __restrict__ bq, const float* __restrict__ bk,
        const float* __restrict__ bv, const float* __restrict__ bo,
        const unsigned short* __restrict__ wfrag,
        float* __restrict__ out2){
    __shared__ float ctxL[4][64][18];   // padded: all access patterns <=2-way (free)
    int tid = threadIdx.x, w = tid >> 6, lane = tid & 63;
    int n = blockIdx.x*4 + w;
    int t = lane & 15, g = lane >> 4;
    int k0 = g * 8;

    f32x4 xv  = *(const f32x4*)(x + (size_t)n*64 + t*4);
    f32x4 ib0 = *(const f32x4*)(in_b + k0);
    f32x4 ib1 = *(const f32x4*)(in_b + k0 + 4);
    f32x4 xp0 = *(const f32x4*)(xpool + (size_t)n*32 + k0);
    f32x4 xp1 = *(const f32x4*)(xpool + (size_t)n*32 + k0 + 4);
    f32x4 iw0a = *(const f32x4*)(in_W + k0),      iw0b = *(const f32x4*)(in_W + k0 + 4);
    f32x4 iw1a = *(const f32x4*)(in_W + 32 + k0), iw1b = *(const f32x4*)(in_W + 32 + k0 + 4);
    f32x4 iw2a = *(const f32x4*)(in_W + 64 + k0), iw2b = *(const f32x4*)(in_W + 64 + k0 + 4);
    f32x4 iw3a = *(const f32x4*)(in_W + 96 + k0), iw3b = *(const f32x4*)(in_W + 96 + k0 + 4);
    f32x4 sA = ib0 + xp0 + xv[0]*iw0a + xv[1]*iw1a + xv[2]*iw2a + xv[3]*iw3a;
    f32x4 sB = ib1 + xp1 + xv[0]*iw0b + xv[1]*iw1b + xv[2]*iw2b + xv[3]*iw3b;
    bf16x8 sfrag = mk8(pk2(sA[0],sA[1]), pk2(sA[2],sA[3]), pk2(sB[0],sB[1]), pk2(sB[2],sB[3]));

    const bf16x8* WF = (const bf16x8*)wfrag;
    f32x4 zero = {0.f, 0.f, 0.f, 0.f};

    int qd0[4], qd1[4], kd0[4], kd1[4], vd0[4], vd1[4];
    #pragma unroll
    for (int b = 0; b < 4; b++){
        bf16x8 wq = WF[(0*4 + b)*64 + lane];
        bf16x8 wk = WF[(1*4 + b)*64 + lane];
        bf16x8 wv = WF[(2*4 + b)*64 + lane];
        f32x4 qc = __builtin_amdgcn_mfma_f32_16x16x32_bf16(wq, sfrag, zero, 0, 0, 0);
        f32x4 kc = __builtin_amdgcn_mfma_f32_16x16x32_bf16(wk, sfrag, zero, 0, 0, 0);
        f32x4 vc = __builtin_amdgcn_mfma_f32_16x16x32_bf16(sfrag, wv, zero, 0, 0, 0);
        f32x4 bq4 = *(const f32x4*)(bq + 16*b + 4*g);
        f32x4 bk4 = *(const f32x4*)(bk + 16*b + 4*g);
        float bvv = bv[16*b + t];
        qc += bq4; kc += bk4;
        vc[0] += bvv; vc[1] += bvv; vc[2] += bvv; vc[3] += bvv;
        qd0[b] = (int)pk2(qc[0], qc[1]); qd1[b] = (int)pk2(qc[2], qc[3]);
        kd0[b] = (int)pk2(kc[0], kc[1]); kd1[b] = (int)pk2(kc[2], kc[3]);
        vd0[b] = (int)pk2(vc[0], vc[1]); vd1[b] = (int)pk2(vc[2], vc[3]);
    }

    int s0l = t + 32*(g & 1);
    int s1l = s0l + 16;
    bool hiz = (g >= 2);
    #pragma unroll
    for (int h = 0; h < 4; h++){
        bf16x8 ka = gather8(kd0[h], kd1[h], s0l, s1l, hiz);
        bf16x8 qb = gather8(qd0[h], qd1[h], s0l, s1l, hiz);
        f32x4 sc = __builtin_amdgcn_mfma_f32_16x16x32_bf16(ka, qb, zero, 0, 0, 0);
        sc *= 0.25f;
        float m = fmaxf(fmaxf(sc[0], sc[1]), fmaxf(sc[2], sc[3]));
        m = fmaxf(m, __shfl_xor(m, 16, 64));
        m = fmaxf(m, __shfl_xor(m, 32, 64));
        float p0 = __expf(sc[0] - m), p1 = __expf(sc[1] - m);
        float p2 = __expf(sc[2] - m), p3 = __expf(sc[3] - m);
        float sum = p0 + p1 + p2 + p3;
        sum += __shfl_xor(sum, 16, 64);
        sum += __shfl_xor(sum, 32, 64);
        float inv = 1.f / sum;
        int pd0 = (int)pk2(p0, p1), pd1 = (int)pk2(p2, p3);
        bf16x8 va = gather8(vd0[h], vd1[h], s0l, s1l, hiz);
        bf16x8 pb = gather8(pd0, pd1, s0l, s1l, hiz);
        f32x4 cx = __builtin_amdgcn_mfma_f32_16x16x32_bf16(va, pb, zero, 0, 0, 0);
        cx *= inv;
        #pragma unroll
        for (int r = 0; r < 4; r++) ctxL[w][h*16 + 4*g + r][t] = cx[r];
    }

    bf16x8 cb[2];
    #pragma unroll
    for (int ks = 0; ks < 2; ks++){
        float c0 = ctxL[w][ks*32 + k0 + 0][t], c1 = ctxL[w][ks*32 + k0 + 1][t];
        float c2 = ctxL[w][ks*32 + k0 + 2][t], c3 = ctxL[w][ks*32 + k0 + 3][t];
        float c4 = ctxL[w][ks*32 + k0 + 4][t], c5 = ctxL[w][ks*32 + k0 + 5][t];
        float c6 = ctxL[w][ks*32 + k0 + 6][t], c7 = ctxL[w][ks*32 + k0 + 7][t];
        cb[ks] = mk8(pk2(c0,c1), pk2(c2,c3), pk2(c4,c5), pk2(c6,c7));
    }
    #pragma unroll
    for (int rb = 0; rb < 2; rb++){
        bf16x8 wo0 = WF[(12 + rb*2 + 0)*64 + lane];
        bf16x8 wo1 = WF[(12 + rb*2 + 1)*64 + lane];
        f32x4 oc = __builtin_amdgcn_mfma_f32_16x16x32_bf16(wo0, cb[0], zero, 0, 0, 0);
        oc = __builtin_amdgcn_mfma_f32_16x16x32_bf16(wo1, cb[1], oc, 0, 0, 0);
        f32x4 bo4 = *(const f32x4*)(bo + 16*rb + 4*g);
        oc += bo4;
        #pragma unroll
        for (int r = 0; r < 4; r++) ctxL[w][16*rb + 4*g + r][t] = oc[r];
    }
    float o[8];
    #pragma unroll
    for (int j = 0; j < 8; j++) o[j] = ctxL[w][g*8 + j][t];
    float* outp = out2 + ((size_t)t*NN + n)*32 + g*8;
    *(f32x4*)outp       = (f32x4){o[0], o[1], o[2], o[3]};
    *((f32x4*)outp + 1) = (f32x4){o[4], o[5], o[6], o[7]};
}

// ---------------- K10: forecast / risk heads ----------------
__global__ __launch_bounds__(256) void head_kernel(const float* __restrict__ out2,
        const float* __restrict__ fW1, const float* __restrict__ fb1,
        const float* __restrict__ fW2, const float* __restrict__ fb2,
        const float* __restrict__ rW1, const float* __restrict__ rb1,
        const float* __restrict__ rW2, const float* __restrict__ rb2,
        float* __restrict__ out0, float* __restrict__ out1){
    int tid = threadIdx.x;
    int wv = tid >> 6, lane = tid & 63;
    int n = blockIdx.x*4 + wv;
    int c = lane & 31, path = lane >> 5;
    const float* W1 = path ? rW1 : fW1;
    const float* b1 = path ? rb1 : fb1;
    const float* W2 = path ? rW2 : fW2;
    const float* b2 = path ? rb2 : fb2;
    const float* last = out2 + ((size_t)15*NN + n)*32;
    float h1 = b1[c];
    #pragma unroll
    for (int k = 0; k < 32; k++) h1 += last[k] * W1[k*32 + c];
    h1 = fmaxf(h1, 0.f);
    float z = h1 * W2[c];
    #pragma unroll
    for (int off = 16; off >= 1; off >>= 1) z += __shfl_xor(z, off, 64);
    if (lane == 0)  out0[n] = fmaxf(z + b2[0], 0.f);
    if (lane == 32) out1[n] = 1.f / (1.f + __expf(-(z + b2[0])));
}

extern "C" void kernel_launch(void* const* d_in, const int* in_sizes, int n_in,
                              void* d_out, int out_size, void* d_ws, size_t ws_size,
                              hipStream_t stream){
    const float* x    = (const float*)d_in[0];
    const int*   ei   = (const int*)  d_in[1];
    const float* ew   = (const float*)d_in[2];
    const float* in_W = (const float*)d_in[3];
    const float* in_b = (const float*)d_in[4];
    const float* Wq = (const float*)d_in[19];
    const float* bq = (const float*)d_in[20];
    const float* Wk = (const float*)d_in[21];
    const float* bk = (const float*)d_in[22];
    const float* Wv = (const float*)d_in[23];
    const float* bv = (const float*)d_in[24];
    const float* Wo = (const float*)d_in[25];
    const float* bo = (const float*)d_in[26];
    const float* fW1 = (const float*)d_in[27];
    const float* fb1 = (const float*)d_in[28];
    const float* fW2 = (const float*)d_in[29];
    const float* fb2 = (const float*)d_in[30];
    const float* rW1 = (const float*)d_in[31];
    const float* rb1 = (const float*)d_in[32];
    const float* rW2 = (const float*)d_in[33];
    const float* rb2 = (const float*)d_in[34];

    float* out0 = (float*)d_out;
    float* out1 = out0 + NN;
    float* out2 = out0 + 2*NN;

    float* ws = (float*)d_ws;
    size_t off = 0;
    unsigned short* xlb = (unsigned short*)(ws + off); off += (size_t)NN*64;  // NN*128 bf16
    float* xr     = ws + off; off += (size_t)NN*128;
    float* xpA    = ws + off; off += (size_t)NN*32;
    float* xpB    = ws + off; off += (size_t)NN*32;
    int* counts   = (int*)(ws + off); off += NN;
    int* offs     = (int*)(ws + off); off += NN + 1;
    int* nxt      = (int*)(ws + off); off += NN + 1;
    off = (off + 1) & ~(size_t)1;            // 8B align for int2
    int2* esrc    = (int2*)(ws + off); off += (size_t)EE*2;
    off = (off + 3) & ~(size_t)3;            // 16B align for bf16x8 loads
    unsigned short* wfrag = (unsigned short*)(ws + off); off += 16*64*8/2;

    hipMemsetAsync(counts, 0, NN*sizeof(int), stream);
    pool_kernel<<<NN/8, 256, 0, stream>>>(x, in_W, in_b, xpA);
    wfrag_kernel<<<16, 64, 0, stream>>>(Wq, Wk, Wv, Wo, wfrag);
    count_kernel<<<(EE+255)/256, 256, 0, stream>>>(ei, counts);
    scan_kernel<<<1, 1024, 0, stream>>>(counts, offs, nxt);
    fill_kernel<<<(EE+255)/256, 256, 0, stream>>>(ei, ew, nxt, esrc);

    for (int layer = 0; layer < 2; layer++){
        const float* Wl   = (const float*)d_in[5 + 7*layer];
        const float* bl   = (const float*)d_in[6 + 7*layer];
        const float* Wr   = (const float*)d_in[7 + 7*layer];
        const float* br   = (const float*)d_in[8 + 7*layer];
        const float* We   = (const float*)d_in[9 + 7*layer];
        const float* att  = (const float*)d_in[10 + 7*layer];
        const float* bias = (const float*)d_in[11 + 7*layer];
        const float* xin  = layer ? xpB : xpA;
        float*       xout = layer ? xpA : xpB;
        linlr_kernel<<<NN/LNODES, 128, 0, stream>>>(xin, Wl, bl, Wr, br, xlb, xr);
        gat_fused_kernel<<<NN, 256, 0, stream>>>(offs, esrc, xlb, xr, We, att, bias, xout);
    }

    temporal_kernel<<<NN/4, 256, 0, stream>>>(x, xpA, in_W, in_b,
                                              bq, bk, bv, bo, wfrag, out2);
    head_kernel<<<NN/4, 256, 0, stream>>>(out2, fW1, fb1, fW2, fb2,
                                          rW1, rb1, rW2, rb2, out0, out1);
}

// Round 7
// 460.884 us; speedup vs baseline: 3.2839x; 1.2540x over previous
//
#include <hip/hip_runtime.h>
#include <hip/hip_bf16.h>

#define NN 50000
#define TT 16
#define DD 4
#define EE 800000
#define HH 4
#define HID 32
#define THID 64
#define HD 16

typedef __attribute__((ext_vector_type(8))) short bf16x8;
typedef __attribute__((ext_vector_type(4))) float f32x4;
typedef __attribute__((ext_vector_type(4))) unsigned u32x4;

__device__ __forceinline__ unsigned short f2bf(float f){
    unsigned u = __float_as_uint(f);
    u = u + 0x7fffu + ((u >> 16) & 1u);   // RNE
    return (unsigned short)(u >> 16);
}
__device__ __forceinline__ unsigned pk2(float a, float b){
    return (unsigned)f2bf(a) | ((unsigned)f2bf(b) << 16);
}
__device__ __forceinline__ bf16x8 mk8(unsigned a0, unsigned a1, unsigned a2, unsigned a3){
    u32x4 u = {a0, a1, a2, a3};
    return __builtin_bit_cast(bf16x8, u);
}
// Build an 8-bf16 operand fragment from a C-fragment's packed dword pair via 4 shfls.
__device__ __forceinline__ bf16x8 gather8(int d0, int d1, int s0, int s1, bool zero){
    int a0 = __shfl(d0, s0, 64);
    int a1 = __shfl(d1, s0, 64);
    int a2 = __shfl(d0, s1, 64);
    int a3 = __shfl(d1, s1, 64);
    if (zero){ a0 = 0; a1 = 0; a2 = 0; a3 = 0; }
    return mk8((unsigned)a0, (unsigned)a1, (unsigned)a2, (unsigned)a3);
}

// ---------------- K1: x_pool = (mean_t x) @ in_W + in_b ----------------
__global__ __launch_bounds__(256) void pool_kernel(const float* __restrict__ x,
        const float* __restrict__ in_W, const float* __restrict__ in_b,
        float* __restrict__ xp){
    __shared__ float xs[512];
    __shared__ float xb[8][4];
    int tid = threadIdx.x;
    size_t base = (size_t)blockIdx.x * 512;
    xs[tid]       = x[base + tid];
    xs[tid + 256] = x[base + tid + 256];
    __syncthreads();
    if (tid < 32){
        int nl = tid >> 2, d = tid & 3;
        float s = 0.f;
        #pragma unroll
        for (int t = 0; t < 16; t++) s += xs[nl*64 + t*4 + d];
        xb[nl][d] = s * (1.f/16.f);
    }
    __syncthreads();
    int nl = tid >> 5, c = tid & 31;
    float v = in_b[c];
    #pragma unroll
    for (int d = 0; d < 4; d++) v += xb[nl][d] * in_W[d*32 + c];
    xp[(size_t)(blockIdx.x*8 + nl)*32 + c] = v;
}

// ---------------- weight -> bf16 MFMA fragments (once per launch) ----------------
__global__ void wfrag_kernel(const float* __restrict__ Wq, const float* __restrict__ Wk,
                             const float* __restrict__ Wv, const float* __restrict__ Wo,
                             unsigned short* __restrict__ frag){
    int fid = blockIdx.x, lane = threadIdx.x;
    const float* W; int b, k0, ncol;
    if (fid < 4)      { W = Wq; b = fid;      k0 = 0;  ncol = 64; }
    else if (fid < 8) { W = Wk; b = fid - 4;  k0 = 0;  ncol = 64; }
    else if (fid < 12){ W = Wv; b = fid - 8;  k0 = 0;  ncol = 64; }
    else { W = Wo; int rb = (fid-12) >> 1, ks = (fid-12) & 1; b = rb; k0 = ks*32; ncol = 32; }
    int col = 16*b + (lane & 15);
    int kk  = k0 + (lane >> 4)*8;
    unsigned short* out = frag + ((size_t)fid*64 + lane)*8;
    #pragma unroll
    for (int j = 0; j < 8; j++) out[j] = f2bf(W[(size_t)(kk + j)*ncol + col]);
}

// ---------------- CSR build ----------------
__global__ void count_kernel(const int* __restrict__ ei, int* __restrict__ counts){
    int e = blockIdx.x*256 + threadIdx.x;
    if (e >= EE) return;
    atomicAdd(&counts[ei[EE + e]], 1);
}

#define SBLK 49   // ceil(NN/1024)

// level 1: per-1024-chunk sums (coalesced int4)
__global__ __launch_bounds__(256) void bsum_kernel(const int* __restrict__ counts,
                                                   int* __restrict__ bsum){
    int b = blockIdx.x, tid = threadIdx.x;
    int base = b*1024 + tid*4;
    int s = 0;
    if (base + 3 < NN){ int4 v = *(const int4*)(counts + base); s = v.x+v.y+v.z+v.w; }
    else { for (int i = 0; i < 4; i++) if (base+i < NN) s += counts[base+i]; }
    #pragma unroll
    for (int off = 1; off < 64; off <<= 1) s += __shfl_xor(s, off, 64);
    __shared__ int wsum[4];
    if ((tid & 63) == 0) wsum[tid >> 6] = s;
    __syncthreads();
    if (tid == 0) bsum[b] = wsum[0] + wsum[1] + wsum[2] + wsum[3];
}

// level 2: per-block 1024-element scan + global offset from bsum prefix
__global__ __launch_bounds__(256) void scan2_kernel(const int* __restrict__ counts,
                                                    const int* __restrict__ bsum,
                                                    int* __restrict__ offs,
                                                    int* __restrict__ nxt){
    int b = blockIdx.x, tid = threadIdx.x;
    __shared__ int lds[256];
    __shared__ int bofs_s;
    if (tid < 64){
        int v = (tid < b) ? bsum[tid] : 0;    // SBLK=49 <= 64
        #pragma unroll
        for (int off = 1; off < 64; off <<= 1) v += __shfl_xor(v, off, 64);
        if (tid == 0) bofs_s = v;
    }
    int base = b*1024 + tid*4;
    int c0=0, c1=0, c2=0, c3=0;
    if (base + 3 < NN){ int4 v = *(const int4*)(counts + base); c0=v.x; c1=v.y; c2=v.z; c3=v.w; }
    else {
        if (base   < NN) c0 = counts[base];
        if (base+1 < NN) c1 = counts[base+1];
        if (base+2 < NN) c2 = counts[base+2];
        if (base+3 < NN) c3 = counts[base+3];
    }
    lds[tid] = c0 + c1 + c2 + c3;
    __syncthreads();
    for (int off = 1; off < 256; off <<= 1){
        int v = (tid >= off) ? lds[tid - off] : 0;
        __syncthreads();
        lds[tid] += v;
        __syncthreads();
    }
    int run = bofs_s + ((tid == 0) ? 0 : lds[tid - 1]);
    if (base   < NN){ offs[base]   = run; nxt[base]   = run; } run += c0;
    if (base+1 < NN){ offs[base+1] = run; nxt[base+1] = run; } run += c1;
    if (base+2 < NN){ offs[base+2] = run; nxt[base+2] = run; } run += c2;
    if (base+3 < NN){ offs[base+3] = run; nxt[base+3] = run; }
    if (b == 0 && tid == 0) offs[NN] = EE;   // total is statically known
}

// materialize CSR-ordered (src, weight) records -> 2-deep load chain in gat kernel
__global__ void fill_kernel(const int* __restrict__ ei, const float* __restrict__ ew,
                            int* __restrict__ nxt, int2* __restrict__ esrc){
    int e = blockIdx.x*256 + threadIdx.x;
    if (e >= EE) return;
    int dst = ei[EE + e];
    int pos = atomicAdd(&nxt[dst], 1);
    esrc[pos] = make_int2(ei[e], __float_as_int(ew[e]));
}

// ---------------- K2: xl(bf16) = xp@Wl+bl ; xr(f32) = xp@Wr+br ----------------
#define LNODES 8
__global__ __launch_bounds__(128) void linlr_kernel(const float* __restrict__ xp,
        const float* __restrict__ Wl, const float* __restrict__ bl,
        const float* __restrict__ Wr, const float* __restrict__ br,
        unsigned short* __restrict__ xlb, float* __restrict__ xr){
    int j = threadIdx.x;
    int n0 = blockIdx.x * LNODES;
    float wl[32], wrr[32];
    #pragma unroll
    for (int k = 0; k < 32; k++){ wl[k] = Wl[k*128 + j]; wrr[k] = Wr[k*128 + j]; }
    float blv = bl[j], brv = br[j];
    __shared__ float xs[LNODES][32];
    int r = j >> 5, c = j & 31;
    #pragma unroll
    for (int q = 0; q < LNODES/4; q++)
        xs[q*4 + r][c] = xp[(size_t)(n0 + q*4 + r)*32 + c];
    __syncthreads();
    #pragma unroll
    for (int m = 0; m < LNODES; m++){
        float al = blv, ar = brv;
        #pragma unroll
        for (int k = 0; k < 32; k++){ float v = xs[m][k]; al += v*wl[k]; ar += v*wrr[k]; }
        xlb[(size_t)(n0+m)*128 + j] = f2bf(al);
        xr[(size_t)(n0+m)*128 + j] = ar;
    }
}

// ---------------- K3: fused GATv2 edge phase, 4 waves strided over edges ----------------
__global__ __launch_bounds__(256) void gat_fused_kernel(
        const int* __restrict__ offs, const int2* __restrict__ esrc,
        const unsigned short* __restrict__ xlb, const float* __restrict__ xr,
        const float* __restrict__ We, const float* __restrict__ att,
        const float* __restrict__ bias, float* __restrict__ xq){
    int n = blockIdx.x;
    int tid = threadIdx.x;
    int w = tid >> 6, lane = tid & 63;
    int c2 = lane << 1;
    float2 xrv  = *(const float2*)(xr + (size_t)n*128 + c2);
    float2 Wev  = *(const float2*)(We + c2);
    float2 attv = *(const float2*)(att + c2);
    int beg = offs[n], end = offs[n+1];
    float acc0 = 0.f, acc1 = 0.f, den = 0.f;
    for (int i = beg + w; i < end; i += 4){
        int2 r = esrc[i];
        int src  = r.x;
        float wt = __int_as_float(r.y);
        unsigned u = *(const unsigned*)(xlb + (size_t)src*128 + c2);
        float xl0 = __uint_as_float(u << 16);
        float xl1 = __uint_as_float(u & 0xffff0000u);
        float m0 = xl0 + xrv.x + wt*Wev.x; m0 = m0 > 0.f ? m0 : 0.2f*m0;
        float m1 = xl1 + xrv.y + wt*Wev.y; m1 = m1 > 0.f ? m1 : 0.2f*m1;
        float z = m0*attv.x + m1*attv.y;
        z += __shfl_xor(z, 1);
        z += __shfl_xor(z, 2);
        z += __shfl_xor(z, 4);
        z += __shfl_xor(z, 8);
        float a = __expf(z);
        den += a; acc0 += a*xl0; acc1 += a*xl1;
    }
    __shared__ float lacc[4][64][2];
    __shared__ float lden[4][64];
    lacc[w][lane][0] = acc0;
    lacc[w][lane][1] = acc1;
    lden[w][lane] = den;
    __syncthreads();
    if (tid < 32){
        float s = 0.f;
        #pragma unroll
        for (int h = 0; h < 4; h++){
            int l = 16*h + (tid >> 1), sl = tid & 1;
            float a = lacc[0][l][sl] + lacc[1][l][sl] + lacc[2][l][sl] + lacc[3][l][sl];
            float d = lden[0][l] + lden[1][l] + lden[2][l] + lden[3][l];
            s += a / (d + 1e-16f);
        }
        s = s*0.25f + bias[tid];
        xq[(size_t)n*32 + tid] = fmaxf(s, 0.f);
    }
}

// ---------------- K9: temporal attention via MFMA, one wave per node ----------------
__global__ __launch_bounds__(256) void temporal_kernel(const float* __restrict__ x,
        const float* __restrict__ xpool,
        const float* __restrict__ in_W, const float* __restrict__ in_b,
        const float* __restrict__ bq, const float* __restrict__ bk,
        const float* __restrict__ bv, const float* __restrict__ bo,
        const unsigned short* __restrict__ wfrag,
        float* __restrict__ out2){
    __shared__ float ctxL[4][64][18];   // padded: all access patterns <=2-way (free)
    int tid = threadIdx.x, w = tid >> 6, lane = tid & 63;
    int n = blockIdx.x*4 + w;
    int t = lane & 15, g = lane >> 4;
    int k0 = g * 8;

    f32x4 xv  = *(const f32x4*)(x + (size_t)n*64 + t*4);
    f32x4 ib0 = *(const f32x4*)(in_b + k0);
    f32x4 ib1 = *(const f32x4*)(in_b + k0 + 4);
    f32x4 xp0 = *(const f32x4*)(xpool + (size_t)n*32 + k0);
    f32x4 xp1 = *(const f32x4*)(xpool + (size_t)n*32 + k0 + 4);
    f32x4 iw0a = *(const f32x4*)(in_W + k0),      iw0b = *(const f32x4*)(in_W + k0 + 4);
    f32x4 iw1a = *(const f32x4*)(in_W + 32 + k0), iw1b = *(const f32x4*)(in_W + 32 + k0 + 4);
    f32x4 iw2a = *(const f32x4*)(in_W + 64 + k0), iw2b = *(const f32x4*)(in_W + 64 + k0 + 4);
    f32x4 iw3a = *(const f32x4*)(in_W + 96 + k0), iw3b = *(const f32x4*)(in_W + 96 + k0 + 4);
    f32x4 sA = ib0 + xp0 + xv[0]*iw0a + xv[1]*iw1a + xv[2]*iw2a + xv[3]*iw3a;
    f32x4 sB = ib1 + xp1 + xv[0]*iw0b + xv[1]*iw1b + xv[2]*iw2b + xv[3]*iw3b;
    bf16x8 sfrag = mk8(pk2(sA[0],sA[1]), pk2(sA[2],sA[3]), pk2(sB[0],sB[1]), pk2(sB[2],sB[3]));

    const bf16x8* WF = (const bf16x8*)wfrag;
    f32x4 zero = {0.f, 0.f, 0.f, 0.f};

    int qd0[4], qd1[4], kd0[4], kd1[4], vd0[4], vd1[4];
    #pragma unroll
    for (int b = 0; b < 4; b++){
        bf16x8 wq = WF[(0*4 + b)*64 + lane];
        bf16x8 wk = WF[(1*4 + b)*64 + lane];
        bf16x8 wv = WF[(2*4 + b)*64 + lane];
        f32x4 qc = __builtin_amdgcn_mfma_f32_16x16x32_bf16(wq, sfrag, zero, 0, 0, 0);
        f32x4 kc = __builtin_amdgcn_mfma_f32_16x16x32_bf16(wk, sfrag, zero, 0, 0, 0);
        f32x4 vc = __builtin_amdgcn_mfma_f32_16x16x32_bf16(sfrag, wv, zero, 0, 0, 0);
        f32x4 bq4 = *(const f32x4*)(bq + 16*b + 4*g);
        f32x4 bk4 = *(const f32x4*)(bk + 16*b + 4*g);
        float bvv = bv[16*b + t];
        qc += bq4; kc += bk4;
        vc[0] += bvv; vc[1] += bvv; vc[2] += bvv; vc[3] += bvv;
        qd0[b] = (int)pk2(qc[0], qc[1]); qd1[b] = (int)pk2(qc[2], qc[3]);
        kd0[b] = (int)pk2(kc[0], kc[1]); kd1[b] = (int)pk2(kc[2], kc[3]);
        vd0[b] = (int)pk2(vc[0], vc[1]); vd1[b] = (int)pk2(vc[2], vc[3]);
    }

    int s0l = t + 32*(g & 1);
    int s1l = s0l + 16;
    bool hiz = (g >= 2);
    #pragma unroll
    for (int h = 0; h < 4; h++){
        bf16x8 ka = gather8(kd0[h], kd1[h], s0l, s1l, hiz);
        bf16x8 qb = gather8(qd0[h], qd1[h], s0l, s1l, hiz);
        f32x4 sc = __builtin_amdgcn_mfma_f32_16x16x32_bf16(ka, qb, zero, 0, 0, 0);
        sc *= 0.25f;
        float m = fmaxf(fmaxf(sc[0], sc[1]), fmaxf(sc[2], sc[3]));
        m = fmaxf(m, __shfl_xor(m, 16, 64));
        m = fmaxf(m, __shfl_xor(m, 32, 64));
        float p0 = __expf(sc[0] - m), p1 = __expf(sc[1] - m);
        float p2 = __expf(sc[2] - m), p3 = __expf(sc[3] - m);
        float sum = p0 + p1 + p2 + p3;
        sum += __shfl_xor(sum, 16, 64);
        sum += __shfl_xor(sum, 32, 64);
        float inv = 1.f / sum;
        int pd0 = (int)pk2(p0, p1), pd1 = (int)pk2(p2, p3);
        bf16x8 va = gather8(vd0[h], vd1[h], s0l, s1l, hiz);
        bf16x8 pb = gather8(pd0, pd1, s0l, s1l, hiz);
        f32x4 cx = __builtin_amdgcn_mfma_f32_16x16x32_bf16(va, pb, zero, 0, 0, 0);
        cx *= inv;
        #pragma unroll
        for (int r = 0; r < 4; r++) ctxL[w][h*16 + 4*g + r][t] = cx[r];
    }

    bf16x8 cb[2];
    #pragma unroll
    for (int ks = 0; ks < 2; ks++){
        float c0 = ctxL[w][ks*32 + k0 + 0][t], c1 = ctxL[w][ks*32 + k0 + 1][t];
        float c2 = ctxL[w][ks*32 + k0 + 2][t], c3 = ctxL[w][ks*32 + k0 + 3][t];
        float c4 = ctxL[w][ks*32 + k0 + 4][t], c5 = ctxL[w][ks*32 + k0 + 5][t];
        float c6 = ctxL[w][ks*32 + k0 + 6][t], c7 = ctxL[w][ks*32 + k0 + 7][t];
        cb[ks] = mk8(pk2(c0,c1), pk2(c2,c3), pk2(c4,c5), pk2(c6,c7));
    }
    #pragma unroll
    for (int rb = 0; rb < 2; rb++){
        bf16x8 wo0 = WF[(12 + rb*2 + 0)*64 + lane];
        bf16x8 wo1 = WF[(12 + rb*2 + 1)*64 + lane];
        f32x4 oc = __builtin_amdgcn_mfma_f32_16x16x32_bf16(wo0, cb[0], zero, 0, 0, 0);
        oc = __builtin_amdgcn_mfma_f32_16x16x32_bf16(wo1, cb[1], oc, 0, 0, 0);
        f32x4 bo4 = *(const f32x4*)(bo + 16*rb + 4*g);
        oc += bo4;
        #pragma unroll
        for (int r = 0; r < 4; r++) ctxL[w][16*rb + 4*g + r][t] = oc[r];
    }
    float o[8];
    #pragma unroll
    for (int j = 0; j < 8; j++) o[j] = ctxL[w][g*8 + j][t];
    float* outp = out2 + ((size_t)t*NN + n)*32 + g*8;
    *(f32x4*)outp       = (f32x4){o[0], o[1], o[2], o[3]};
    *((f32x4*)outp + 1) = (f32x4){o[4], o[5], o[6], o[7]};
}

// ---------------- K10: forecast / risk heads ----------------
__global__ __launch_bounds__(256) void head_kernel(const float* __restrict__ out2,
        const float* __restrict__ fW1, const float* __restrict__ fb1,
        const float* __restrict__ fW2, const float* __restrict__ fb2,
        const float* __restrict__ rW1, const float* __restrict__ rb1,
        const float* __restrict__ rW2, const float* __restrict__ rb2,
        float* __restrict__ out0, float* __restrict__ out1){
    int tid = threadIdx.x;
    int wv = tid >> 6, lane = tid & 63;
    int n = blockIdx.x*4 + wv;
    int c = lane & 31, path = lane >> 5;
    const float* W1 = path ? rW1 : fW1;
    const float* b1 = path ? rb1 : fb1;
    const float* W2 = path ? rW2 : fW2;
    const float* b2 = path ? rb2 : fb2;
    const float* last = out2 + ((size_t)15*NN + n)*32;
    float h1 = b1[c];
    #pragma unroll
    for (int k = 0; k < 32; k++) h1 += last[k] * W1[k*32 + c];
    h1 = fmaxf(h1, 0.f);
    float z = h1 * W2[c];
    #pragma unroll
    for (int off = 16; off >= 1; off >>= 1) z += __shfl_xor(z, off, 64);
    if (lane == 0)  out0[n] = fmaxf(z + b2[0], 0.f);
    if (lane == 32) out1[n] = 1.f / (1.f + __expf(-(z + b2[0])));
}

extern "C" void kernel_launch(void* const* d_in, const int* in_sizes, int n_in,
                              void* d_out, int out_size, void* d_ws, size_t ws_size,
                              hipStream_t stream){
    const float* x    = (const float*)d_in[0];
    const int*   ei   = (const int*)  d_in[1];
    const float* ew   = (const float*)d_in[2];
    const float* in_W = (const float*)d_in[3];
    const float* in_b = (const float*)d_in[4];
    const float* Wq = (const float*)d_in[19];
    const float* bq = (const float*)d_in[20];
    const float* Wk = (const float*)d_in[21];
    const float* bk = (const float*)d_in[22];
    const float* Wv = (const float*)d_in[23];
    const float* bv = (const float*)d_in[24];
    const float* Wo = (const float*)d_in[25];
    const float* bo = (const float*)d_in[26];
    const float* fW1 = (const float*)d_in[27];
    const float* fb1 = (const float*)d_in[28];
    const float* fW2 = (const float*)d_in[29];
    const float* fb2 = (const float*)d_in[30];
    const float* rW1 = (const float*)d_in[31];
    const float* rb1 = (const float*)d_in[32];
    const float* rW2 = (const float*)d_in[33];
    const float* rb2 = (const float*)d_in[34];

    float* out0 = (float*)d_out;
    float* out1 = out0 + NN;
    float* out2 = out0 + 2*NN;

    float* ws = (float*)d_ws;
    size_t off = 0;
    unsigned short* xlb = (unsigned short*)(ws + off); off += (size_t)NN*64;  // NN*128 bf16
    float* xr     = ws + off; off += (size_t)NN*128;
    float* xpA    = ws + off; off += (size_t)NN*32;
    float* xpB    = ws + off; off += (size_t)NN*32;
    int* counts   = (int*)(ws + off); off += NN;
    int* offs     = (int*)(ws + off); off += NN + 1;
    int* nxt      = (int*)(ws + off); off += NN + 1;
    int* bsum     = (int*)(ws + off); off += SBLK;
    off = (off + 1) & ~(size_t)1;            // 8B align for int2
    int2* esrc    = (int2*)(ws + off); off += (size_t)EE*2;
    off = (off + 3) & ~(size_t)3;            // 16B align for bf16x8 loads
    unsigned short* wfrag = (unsigned short*)(ws + off); off += 16*64*8/2;

    hipMemsetAsync(counts, 0, NN*sizeof(int), stream);
    pool_kernel<<<NN/8, 256, 0, stream>>>(x, in_W, in_b, xpA);
    wfrag_kernel<<<16, 64, 0, stream>>>(Wq, Wk, Wv, Wo, wfrag);
    count_kernel<<<(EE+255)/256, 256, 0, stream>>>(ei, counts);
    bsum_kernel<<<SBLK, 256, 0, stream>>>(counts, bsum);
    scan2_kernel<<<SBLK, 256, 0, stream>>>(counts, bsum, offs, nxt);
    fill_kernel<<<(EE+255)/256, 256, 0, stream>>>(ei, ew, nxt, esrc);

    for (int layer = 0; layer < 2; layer++){
        const float* Wl   = (const float*)d_in[5 + 7*layer];
        const float* bl   = (const float*)d_in[6 + 7*layer];
        const float* Wr   = (const float*)d_in[7 + 7*layer];
        const float* br   = (const float*)d_in[8 + 7*layer];
        const float* We   = (const float*)d_in[9 + 7*layer];
        const float* att  = (const float*)d_in[10 + 7*layer];
        const float* bias = (const float*)d_in[11 + 7*layer];
        const float* xin  = layer ? xpB : xpA;
        float*       xout = layer ? xpA : xpB;
        linlr_kernel<<<NN/LNODES, 128, 0, stream>>>(xin, Wl, bl, Wr, br, xlb, xr);
        gat_fused_kernel<<<NN, 256, 0, stream>>>(offs, esrc, xlb, xr, We, att, bias, xout);
    }

    temporal_kernel<<<NN/4, 256, 0, stream>>>(x, xpA, in_W, in_b,
                                              bq, bk, bv, bo, wfrag, out2);
    head_kernel<<<NN/4, 256, 0, stream>>>(out2, fW1, fb1, fW2, fb2,
                                          rW1, rb1, rW2, rb2, out0, out1);
}

// Round 9
// 404.355 us; speedup vs baseline: 3.7430x; 1.1398x over previous
//
#include <hip/hip_runtime.h>
#include <hip/hip_bf16.h>

#define NN 50000
#define TT 16
#define DD 4
#define EE 800000
#define HH 4
#define HID 32
#define THID 64
#define HD 16

typedef __attribute__((ext_vector_type(8))) short bf16x8;
typedef __attribute__((ext_vector_type(4))) float f32x4;
typedef __attribute__((ext_vector_type(2))) float f32x2;
typedef __attribute__((ext_vector_type(4))) unsigned u32x4;
typedef __attribute__((ext_vector_type(4))) _Float16 h4;

__device__ __forceinline__ unsigned short f2bf(float f){
    unsigned u = __float_as_uint(f);
    u = u + 0x7fffu + ((u >> 16) & 1u);   // RNE
    return (unsigned short)(u >> 16);
}
__device__ __forceinline__ unsigned pk2(float a, float b){
    return (unsigned)f2bf(a) | ((unsigned)f2bf(b) << 16);
}
__device__ __forceinline__ bf16x8 mk8(unsigned a0, unsigned a1, unsigned a2, unsigned a3){
    u32x4 u = {a0, a1, a2, a3};
    return __builtin_bit_cast(bf16x8, u);
}
// Build an 8-bf16 operand fragment from a C-fragment's packed dword pair via 4 shfls.
__device__ __forceinline__ bf16x8 gather8(int d0, int d1, int s0, int s1, bool zero){
    int a0 = __shfl(d0, s0, 64);
    int a1 = __shfl(d1, s0, 64);
    int a2 = __shfl(d0, s1, 64);
    int a3 = __shfl(d1, s1, 64);
    if (zero){ a0 = 0; a1 = 0; a2 = 0; a3 = 0; }
    return mk8((unsigned)a0, (unsigned)a1, (unsigned)a2, (unsigned)a3);
}

// ---------------- K1: x_pool = (mean_t x) @ in_W + in_b ----------------
__global__ __launch_bounds__(256) void pool_kernel(const float* __restrict__ x,
        const float* __restrict__ in_W, const float* __restrict__ in_b,
        float* __restrict__ xp){
    __shared__ float xs[512];
    __shared__ float xb[8][4];
    int tid = threadIdx.x;
    size_t base = (size_t)blockIdx.x * 512;
    xs[tid]       = x[base + tid];
    xs[tid + 256] = x[base + tid + 256];
    __syncthreads();
    if (tid < 32){
        int nl = tid >> 2, d = tid & 3;
        float s = 0.f;
        #pragma unroll
        for (int t = 0; t < 16; t++) s += xs[nl*64 + t*4 + d];
        xb[nl][d] = s * (1.f/16.f);
    }
    __syncthreads();
    int nl = tid >> 5, c = tid & 31;
    float v = in_b[c];
    #pragma unroll
    for (int d = 0; d < 4; d++) v += xb[nl][d] * in_W[d*32 + c];
    xp[(size_t)(blockIdx.x*8 + nl)*32 + c] = v;
}

// ---------------- weight -> bf16 MFMA fragments (once per launch) ----------------
__global__ void wfrag_kernel(const float* __restrict__ Wq, const float* __restrict__ Wk,
                             const float* __restrict__ Wv, const float* __restrict__ Wo,
                             unsigned short* __restrict__ frag){
    int fid = blockIdx.x, lane = threadIdx.x;
    const float* W; int b, k0, ncol;
    if (fid < 4)      { W = Wq; b = fid;      k0 = 0;  ncol = 64; }
    else if (fid < 8) { W = Wk; b = fid - 4;  k0 = 0;  ncol = 64; }
    else if (fid < 12){ W = Wv; b = fid - 8;  k0 = 0;  ncol = 64; }
    else { W = Wo; int rb = (fid-12) >> 1, ks = (fid-12) & 1; b = rb; k0 = ks*32; ncol = 32; }
    int col = 16*b + (lane & 15);
    int kk  = k0 + (lane >> 4)*8;
    unsigned short* out = frag + ((size_t)fid*64 + lane)*8;
    #pragma unroll
    for (int j = 0; j < 8; j++) out[j] = f2bf(W[(size_t)(kk + j)*ncol + col]);
}

// ---------------- CSR build ----------------
__global__ void count_kernel(const int* __restrict__ ei, int* __restrict__ counts){
    int e = blockIdx.x*256 + threadIdx.x;
    if (e >= EE) return;
    atomicAdd(&counts[ei[EE + e]], 1);
}

#define SBLK 49   // ceil(NN/1024)

// level 1: per-1024-chunk sums (coalesced int4)
__global__ __launch_bounds__(256) void bsum_kernel(const int* __restrict__ counts,
                                                   int* __restrict__ bsum){
    int b = blockIdx.x, tid = threadIdx.x;
    int base = b*1024 + tid*4;
    int s = 0;
    if (base + 3 < NN){ int4 v = *(const int4*)(counts + base); s = v.x+v.y+v.z+v.w; }
    else { for (int i = 0; i < 4; i++) if (base+i < NN) s += counts[base+i]; }
    #pragma unroll
    for (int off = 1; off < 64; off <<= 1) s += __shfl_xor(s, off, 64);
    __shared__ int wsum[4];
    if ((tid & 63) == 0) wsum[tid >> 6] = s;
    __syncthreads();
    if (tid == 0) bsum[b] = wsum[0] + wsum[1] + wsum[2] + wsum[3];
}

// level 2: per-block 1024-element scan + global offset from bsum prefix
__global__ __launch_bounds__(256) void scan2_kernel(const int* __restrict__ counts,
                                                    const int* __restrict__ bsum,
                                                    int* __restrict__ offs,
                                                    int* __restrict__ nxt){
    int b = blockIdx.x, tid = threadIdx.x;
    __shared__ int lds[256];
    __shared__ int bofs_s;
    if (tid < 64){
        int v = (tid < b) ? bsum[tid] : 0;    // SBLK=49 <= 64
        #pragma unroll
        for (int off = 1; off < 64; off <<= 1) v += __shfl_xor(v, off, 64);
        if (tid == 0) bofs_s = v;
    }
    int base = b*1024 + tid*4;
    int c0=0, c1=0, c2=0, c3=0;
    if (base + 3 < NN){ int4 v = *(const int4*)(counts + base); c0=v.x; c1=v.y; c2=v.z; c3=v.w; }
    else {
        if (base   < NN) c0 = counts[base];
        if (base+1 < NN) c1 = counts[base+1];
        if (base+2 < NN) c2 = counts[base+2];
        if (base+3 < NN) c3 = counts[base+3];
    }
    lds[tid] = c0 + c1 + c2 + c3;
    __syncthreads();
    for (int off = 1; off < 256; off <<= 1){
        int v = (tid >= off) ? lds[tid - off] : 0;
        __syncthreads();
        lds[tid] += v;
        __syncthreads();
    }
    int run = bofs_s + ((tid == 0) ? 0 : lds[tid - 1]);
    if (base   < NN){ offs[base]   = run; nxt[base]   = run; } run += c0;
    if (base+1 < NN){ offs[base+1] = run; nxt[base+1] = run; } run += c1;
    if (base+2 < NN){ offs[base+2] = run; nxt[base+2] = run; } run += c2;
    if (base+3 < NN){ offs[base+3] = run; nxt[base+3] = run; }
    if (b == 0 && tid == 0) offs[NN] = EE;   // total is statically known
}

// materialize CSR-ordered (src, weight) records -> 2-deep load chain in gat kernel
__global__ void fill_kernel(const int* __restrict__ ei, const float* __restrict__ ew,
                            int* __restrict__ nxt, int2* __restrict__ esrc){
    int e = blockIdx.x*256 + threadIdx.x;
    if (e >= EE) return;
    int dst = ei[EE + e];
    int pos = atomicAdd(&nxt[dst], 1);
    esrc[pos] = make_int2(ei[e], __float_as_int(ew[e]));
}

// ---------------- K2: xl,xr (fp16) = xp@Wl+bl, xp@Wr+br ----------------
#define LNODES 8
__global__ __launch_bounds__(128) void linlr_kernel(const float* __restrict__ xp,
        const float* __restrict__ Wl, const float* __restrict__ bl,
        const float* __restrict__ Wr, const float* __restrict__ br,
        _Float16* __restrict__ xlh, _Float16* __restrict__ xrh){
    int j = threadIdx.x;
    int n0 = blockIdx.x * LNODES;
    float wl[32], wrr[32];
    #pragma unroll
    for (int k = 0; k < 32; k++){ wl[k] = Wl[k*128 + j]; wrr[k] = Wr[k*128 + j]; }
    float blv = bl[j], brv = br[j];
    __shared__ float xs[LNODES][32];
    int r = j >> 5, c = j & 31;
    #pragma unroll
    for (int q = 0; q < LNODES/4; q++)
        xs[q*4 + r][c] = xp[(size_t)(n0 + q*4 + r)*32 + c];
    __syncthreads();
    #pragma unroll
    for (int m = 0; m < LNODES; m++){
        float al = blv, ar = brv;
        #pragma unroll
        for (int k = 0; k < 32; k++){ float v = xs[m][k]; al += v*wl[k]; ar += v*wrr[k]; }
        xlh[(size_t)(n0+m)*128 + j] = (_Float16)al;
        xrh[(size_t)(n0+m)*128 + j] = (_Float16)ar;
    }
}

// ---------------- K3: fused GATv2 edge phase, packed fp16 (h4), 2 edges/wave ----------------
// lane: half = lane>>5 picks edge, l2 = lane&31; head = l2>>3; 4 channels/lane via h4.
// leakyrelu(m) == max(m, 0.2*m). softmax shift-invariance: |logit| small, exp() direct.
__global__ __launch_bounds__(256) void gat_fused_kernel(
        const int* __restrict__ offs, const int2* __restrict__ esrc,
        const _Float16* __restrict__ xlh, const _Float16* __restrict__ xrh,
        const float* __restrict__ We, const float* __restrict__ att,
        const float* __restrict__ bias, float* __restrict__ xq){
    int n = blockIdx.x;
    int tid = threadIdx.x;
    int w = tid >> 6, lane = tid & 63;
    int half = lane >> 5, l2 = lane & 31;
    int cb = (l2 >> 3)*32 + (l2 & 7)*4;     // channel base (4 consecutive, one head)

    h4 xr4 = __builtin_bit_cast(h4, *(const f32x2*)(xrh + (size_t)n*128 + cb));
    f32x4 wef = {We[cb], We[cb+1], We[cb+2], We[cb+3]};
    h4 We4 = {(_Float16)wef[0], (_Float16)wef[1], (_Float16)wef[2], (_Float16)wef[3]};
    f32x4 atf = {att[cb], att[cb+1], att[cb+2], att[cb+3]};
    h4 at4 = {(_Float16)atf[0], (_Float16)atf[1], (_Float16)atf[2], (_Float16)atf[3]};

    int beg = offs[n], end = offs[n+1];
    float acc0 = 0.f, acc1 = 0.f, acc2 = 0.f, acc3 = 0.f, den = 0.f;
    for (int i = beg + 2*w; i < end; i += 8){
        int e = i + half;
        bool valid = e < end;
        int ec = valid ? e : end - 1;
        int2 r = esrc[ec];
        int src  = r.x;
        float wt = __int_as_float(r.y);
        h4 xl4 = __builtin_bit_cast(h4, *(const f32x2*)(xlh + (size_t)src*128 + cb));
        h4 m = xl4 + xr4 + We4 * (_Float16)wt;
        h4 rr = __builtin_elementwise_max(m, m * (_Float16)0.2f);
        h4 zp = at4 * rr;
        float z = (float)zp[0] + (float)zp[1] + (float)zp[2] + (float)zp[3];
        z += __shfl_xor(z, 1);
        z += __shfl_xor(z, 2);
        z += __shfl_xor(z, 4);
        float a = valid ? __expf(z) : 0.f;
        den  += a;
        acc0 += a * (float)xl4[0];
        acc1 += a * (float)xl4[1];
        acc2 += a * (float)xl4[2];
        acc3 += a * (float)xl4[3];
    }
    __shared__ float lacc[4][64][4];
    __shared__ float lden[4][64];
    lacc[w][lane][0] = acc0;
    lacc[w][lane][1] = acc1;
    lacc[w][lane][2] = acc2;
    lacc[w][lane][3] = acc3;
    lden[w][lane] = den;
    __syncthreads();
    if (tid < 32){
        int j = tid;
        float s = 0.f;
        #pragma unroll
        for (int h = 0; h < 4; h++){
            int lb = h*8 + (j >> 2);
            int sub = j & 3;
            float av = 0.f, dv = 0.f;
            #pragma unroll
            for (int ww = 0; ww < 4; ww++){
                av += lacc[ww][lb][sub] + lacc[ww][lb + 32][sub];
                dv += lden[ww][lb] + lden[ww][lb + 32];
            }
            s += av / (dv + 1e-16f);
        }
        s = s*0.25f + bias[j];
        xq[(size_t)n*32 + j] = fmaxf(s, 0.f);
    }
}

// ---------------- K9: temporal attention via MFMA, one wave per node ----------------
__global__ __launch_bounds__(256) void temporal_kernel(const float* __restrict__ x,
        const float* __restrict__ xpool,
        const float* __restrict__ in_W, const float* __restrict__ in_b,
        const float* __restrict__ bq, const float* __restrict__ bk,
        const float* __restrict__ bv, const float* __restrict__ bo,
        const unsigned short* __restrict__ wfrag,
        float* __restrict__ out2){
    __shared__ float ctxL[4][64][18];   // padded: all access patterns <=2-way (free)
    int tid = threadIdx.x, w = tid >> 6, lane = tid & 63;
    int n = blockIdx.x*4 + w;
    int t = lane & 15, g = lane >> 4;
    int k0 = g * 8;

    f32x4 xv  = *(const f32x4*)(x + (size_t)n*64 + t*4);
    f32x4 ib0 = *(const f32x4*)(in_b + k0);
    f32x4 ib1 = *(const f32x4*)(in_b + k0 + 4);
    f32x4 xp0 = *(const f32x4*)(xpool + (size_t)n*32 + k0);
    f32x4 xp1 = *(const f32x4*)(xpool + (size_t)n*32 + k0 + 4);
    f32x4 iw0a = *(const f32x4*)(in_W + k0),      iw0b = *(const f32x4*)(in_W + k0 + 4);
    f32x4 iw1a = *(const f32x4*)(in_W + 32 + k0), iw1b = *(const f32x4*)(in_W + 32 + k0 + 4);
    f32x4 iw2a = *(const f32x4*)(in_W + 64 + k0), iw2b = *(const f32x4*)(in_W + 64 + k0 + 4);
    f32x4 iw3a = *(const f32x4*)(in_W + 96 + k0), iw3b = *(const f32x4*)(in_W + 96 + k0 + 4);
    f32x4 sA = ib0 + xp0 + xv[0]*iw0a + xv[1]*iw1a + xv[2]*iw2a + xv[3]*iw3a;
    f32x4 sB = ib1 + xp1 + xv[0]*iw0b + xv[1]*iw1b + xv[2]*iw2b + xv[3]*iw3b;
    bf16x8 sfrag = mk8(pk2(sA[0],sA[1]), pk2(sA[2],sA[3]), pk2(sB[0],sB[1]), pk2(sB[2],sB[3]));

    const bf16x8* WF = (const bf16x8*)wfrag;
    f32x4 zero = {0.f, 0.f, 0.f, 0.f};

    int qd0[4], qd1[4], kd0[4], kd1[4], vd0[4], vd1[4];
    #pragma unroll
    for (int b = 0; b < 4; b++){
        bf16x8 wq = WF[(0*4 + b)*64 + lane];
        bf16x8 wk = WF[(1*4 + b)*64 + lane];
        bf16x8 wv = WF[(2*4 + b)*64 + lane];
        f32x4 qc = __builtin_amdgcn_mfma_f32_16x16x32_bf16(wq, sfrag, zero, 0, 0, 0);
        f32x4 kc = __builtin_amdgcn_mfma_f32_16x16x32_bf16(wk, sfrag, zero, 0, 0, 0);
        f32x4 vc = __builtin_amdgcn_mfma_f32_16x16x32_bf16(sfrag, wv, zero, 0, 0, 0);
        f32x4 bq4 = *(const f32x4*)(bq + 16*b + 4*g);
        f32x4 bk4 = *(const f32x4*)(bk + 16*b + 4*g);
        float bvv = bv[16*b + t];
        qc += bq4; kc += bk4;
        vc[0] += bvv; vc[1] += bvv; vc[2] += bvv; vc[3] += bvv;
        qd0[b] = (int)pk2(qc[0], qc[1]); qd1[b] = (int)pk2(qc[2], qc[3]);
        kd0[b] = (int)pk2(kc[0], kc[1]); kd1[b] = (int)pk2(kc[2], kc[3]);
        vd0[b] = (int)pk2(vc[0], vc[1]); vd1[b] = (int)pk2(vc[2], vc[3]);
    }

    int s0l = t + 32*(g & 1);
    int s1l = s0l + 16;
    bool hiz = (g >= 2);
    #pragma unroll
    for (int h = 0; h < 4; h++){
        bf16x8 ka = gather8(kd0[h], kd1[h], s0l, s1l, hiz);
        bf16x8 qb = gather8(qd0[h], qd1[h], s0l, s1l, hiz);
        f32x4 sc = __builtin_amdgcn_mfma_f32_16x16x32_bf16(ka, qb, zero, 0, 0, 0);
        sc *= 0.25f;
        float m = fmaxf(fmaxf(sc[0], sc[1]), fmaxf(sc[2], sc[3]));
        m = fmaxf(m, __shfl_xor(m, 16, 64));
        m = fmaxf(m, __shfl_xor(m, 32, 64));
        float p0 = __expf(sc[0] - m), p1 = __expf(sc[1] - m);
        float p2 = __expf(sc[2] - m), p3 = __expf(sc[3] - m);
        float sum = p0 + p1 + p2 + p3;
        sum += __shfl_xor(sum, 16, 64);
        sum += __shfl_xor(sum, 32, 64);
        float inv = 1.f / sum;
        int pd0 = (int)pk2(p0, p1), pd1 = (int)pk2(p2, p3);
        bf16x8 va = gather8(vd0[h], vd1[h], s0l, s1l, hiz);
        bf16x8 pb = gather8(pd0, pd1, s0l, s1l, hiz);
        f32x4 cx = __builtin_amdgcn_mfma_f32_16x16x32_bf16(va, pb, zero, 0, 0, 0);
        cx *= inv;
        #pragma unroll
        for (int r = 0; r < 4; r++) ctxL[w][h*16 + 4*g + r][t] = cx[r];
    }

    bf16x8 cb[2];
    #pragma unroll
    for (int ks = 0; ks < 2; ks++){
        float c0 = ctxL[w][ks*32 + k0 + 0][t], c1 = ctxL[w][ks*32 + k0 + 1][t];
        float c2 = ctxL[w][ks*32 + k0 + 2][t], c3 = ctxL[w][ks*32 + k0 + 3][t];
        float c4 = ctxL[w][ks*32 + k0 + 4][t], c5 = ctxL[w][ks*32 + k0 + 5][t];
        float c6 = ctxL[w][ks*32 + k0 + 6][t], c7 = ctxL[w][ks*32 + k0 + 7][t];
        cb[ks] = mk8(pk2(c0,c1), pk2(c2,c3), pk2(c4,c5), pk2(c6,c7));
    }
    #pragma unroll
    for (int rb = 0; rb < 2; rb++){
        bf16x8 wo0 = WF[(12 + rb*2 + 0)*64 + lane];
        bf16x8 wo1 = WF[(12 + rb*2 + 1)*64 + lane];
        f32x4 oc = __builtin_amdgcn_mfma_f32_16x16x32_bf16(wo0, cb[0], zero, 0, 0, 0);
        oc = __builtin_amdgcn_mfma_f32_16x16x32_bf16(wo1, cb[1], oc, 0, 0, 0);
        f32x4 bo4 = *(const f32x4*)(bo + 16*rb + 4*g);
        oc += bo4;
        #pragma unroll
        for (int r = 0; r < 4; r++) ctxL[w][16*rb + 4*g + r][t] = oc[r];
    }
    float o[8];
    #pragma unroll
    for (int j = 0; j < 8; j++) o[j] = ctxL[w][g*8 + j][t];
    float* outp = out2 + ((size_t)t*NN + n)*32 + g*8;
    *(f32x4*)outp       = (f32x4){o[0], o[1], o[2], o[3]};
    *((f32x4*)outp + 1) = (f32x4){o[4], o[5], o[6], o[7]};
}

// ---------------- K10: forecast / risk heads ----------------
__global__ __launch_bounds__(256) void head_kernel(const float* __restrict__ out2,
        const float* __restrict__ fW1, const float* __restrict__ fb1,
        const float* __restrict__ fW2, const float* __restrict__ fb2,
        const float* __restrict__ rW1, const float* __restrict__ rb1,
        const float* __restrict__ rW2, const float* __restrict__ rb2,
        float* __restrict__ out0, float* __restrict__ out1){
    int tid = threadIdx.x;
    int wv = tid >> 6, lane = tid & 63;
    int n = blockIdx.x*4 + wv;
    int c = lane & 31, path = lane >> 5;
    const float* W1 = path ? rW1 : fW1;
    const float* b1 = path ? rb1 : fb1;
    const float* W2 = path ? rW2 : fW2;
    const float* b2 = path ? rb2 : fb2;
    const float* last = out2 + ((size_t)15*NN + n)*32;
    float h1 = b1[c];
    #pragma unroll
    for (int k = 0; k < 32; k++) h1 += last[k] * W1[k*32 + c];
    h1 = fmaxf(h1, 0.f);
    float z = h1 * W2[c];
    #pragma unroll
    for (int off = 16; off >= 1; off >>= 1) z += __shfl_xor(z, off, 64);
    if (lane == 0)  out0[n] = fmaxf(z + b2[0], 0.f);
    if (lane == 32) out1[n] = 1.f / (1.f + __expf(-(z + b2[0])));
}

extern "C" void kernel_launch(void* const* d_in, const int* in_sizes, int n_in,
                              void* d_out, int out_size, void* d_ws, size_t ws_size,
                              hipStream_t stream){
    const float* x    = (const float*)d_in[0];
    const int*   ei   = (const int*)  d_in[1];
    const float* ew   = (const float*)d_in[2];
    const float* in_W = (const float*)d_in[3];
    const float* in_b = (const float*)d_in[4];
    const float* Wq = (const float*)d_in[19];
    const float* bq = (const float*)d_in[20];
    const float* Wk = (const float*)d_in[21];
    const float* bk = (const float*)d_in[22];
    const float* Wv = (const float*)d_in[23];
    const float* bv = (const float*)d_in[24];
    const float* Wo = (const float*)d_in[25];
    const float* bo = (const float*)d_in[26];
    const float* fW1 = (const float*)d_in[27];
    const float* fb1 = (const float*)d_in[28];
    const float* fW2 = (const float*)d_in[29];
    const float* fb2 = (const float*)d_in[30];
    const float* rW1 = (const float*)d_in[31];
    const float* rb1 = (const float*)d_in[32];
    const float* rW2 = (const float*)d_in[33];
    const float* rb2 = (const float*)d_in[34];

    float* out0 = (float*)d_out;
    float* out1 = out0 + NN;
    float* out2 = out0 + 2*NN;

    float* ws = (float*)d_ws;
    size_t off = 0;
    _Float16* xlh = (_Float16*)(ws + off); off += (size_t)NN*64;   // NN*128 fp16
    _Float16* xrh = (_Float16*)(ws + off); off += (size_t)NN*64;
    float* xpA    = ws + off; off += (size_t)NN*32;
    float* xpB    = ws + off; off += (size_t)NN*32;
    int* counts   = (int*)(ws + off); off += NN;
    int* offs     = (int*)(ws + off); off += NN + 1;
    int* nxt      = (int*)(ws + off); off += NN + 1;
    int* bsum     = (int*)(ws + off); off += SBLK;
    off = (off + 1) & ~(size_t)1;            // 8B align for int2
    int2* esrc    = (int2*)(ws + off); off += (size_t)EE*2;
    off = (off + 3) & ~(size_t)3;            // 16B align for bf16x8 loads
    unsigned short* wfrag = (unsigned short*)(ws + off); off += 16*64*8/2;

    hipMemsetAsync(counts, 0, NN*sizeof(int), stream);
    pool_kernel<<<NN/8, 256, 0, stream>>>(x, in_W, in_b, xpA);
    wfrag_kernel<<<16, 64, 0, stream>>>(Wq, Wk, Wv, Wo, wfrag);
    count_kernel<<<(EE+255)/256, 256, 0, stream>>>(ei, counts);
    bsum_kernel<<<SBLK, 256, 0, stream>>>(counts, bsum);
    scan2_kernel<<<SBLK, 256, 0, stream>>>(counts, bsum, offs, nxt);
    fill_kernel<<<(EE+255)/256, 256, 0, stream>>>(ei, ew, nxt, esrc);

    for (int layer = 0; layer < 2; layer++){
        const float* Wl   = (const float*)d_in[5 + 7*layer];
        const float* bl   = (const float*)d_in[6 + 7*layer];
        const float* Wr   = (const float*)d_in[7 + 7*layer];
        const float* br   = (const float*)d_in[8 + 7*layer];
        const float* We   = (const float*)d_in[9 + 7*layer];
        const float* att  = (const float*)d_in[10 + 7*layer];
        const float* bias = (const float*)d_in[11 + 7*layer];
        const float* xin  = layer ? xpB : xpA;
        float*       xout = layer ? xpA : xpB;
        linlr_kernel<<<NN/LNODES, 128, 0, stream>>>(xin, Wl, bl, Wr, br, xlh, xrh);
        gat_fused_kernel<<<NN, 256, 0, stream>>>(offs, esrc, xlh, xrh, We, att, bias, xout);
    }

    temporal_kernel<<<NN/4, 256, 0, stream>>>(x, xpA, in_W, in_b,
                                              bq, bk, bv, bo, wfrag, out2);
    head_kernel<<<NN/4, 256, 0, stream>>>(out2, fW1, fb1, fW2, fb2,
                                          rW1, rb1, rW2, rb2, out0, out1);
}